// Round 1
// baseline (5204.588 us; speedup 1.0000x reference)
//
#include <hip/hip_runtime.h>

#define N_    2048
#define CIN   16
#define T_    8
#define VM_   42
#define COUT  64
#define NODES (N_*T_*VM_)        // 688128
#define EINC  (4*NODES)          // 2752512
#define EMB   336
#define PERN  (T_*VM_*COUT)      // 21504
#define XPERN (CIN*T_*VM_)       // 5376

// ---- ws layout (floats) ----
static const size_t O_A   = 0;                       // xt, later h  (44,040,192)
static const size_t SZ_AB = (size_t)NODES*64;
static const size_t O_B   = SZ_AB;                   // e raw        (44,040,192)
static const size_t O_SEQ = 2*SZ_AB;                 // seq          ( 5,505,024)
static const size_t SZ_SEQ= (size_t)N_*8*EMB;
static const size_t O_AO  = O_SEQ+SZ_SEQ;            // attn out     ( 5,505,024)
static const size_t O_D   = O_AO+SZ_SEQ;             // Dinv         (   688,128)
static const size_t O_Bd  = O_D+NODES;               // Binv         (   688,128)
static const size_t O_BN  = O_Bd+NODES;              // bn sums/scale(        64)
static const size_t O_W   = O_BN+64;                 // Wq,Wk,Wv eff (338688) + Wfc_eff (903168)
static const size_t O_BE  = O_W + 3*EMB*EMB + (size_t)8*EMB*EMB;  // 1008 + 2688 biases

__global__ __launch_bounds__(256) void k_bn_stats(const float* __restrict__ x, float* __restrict__ bn){
    int row  = blockIdx.x*4 + (threadIdx.x>>6);   // row = n*16+ci, 32768 rows
    int lane = threadIdx.x & 63;
    const float* base = x + (size_t)(row>>4)*XPERN + (size_t)(row&15)*EMB;
    float s=0.f, q=0.f;
    for(int k=lane;k<EMB;k+=64){ float v=base[k]; s+=v; q+=v*v; }
    for(int off=32;off;off>>=1){ s+=__shfl_down(s,off); q+=__shfl_down(q,off); }
    if(lane==0){ atomicAdd(bn+(row&15), s); atomicAdd(bn+16+(row&15), q); }
}

__global__ void k_bn_final(float* bn, const float* __restrict__ g, const float* __restrict__ b){
    int c = threadIdx.x;
    if(c<16){
        const float inv = 1.f/(float)NODES;
        float mean = bn[c]*inv;
        float var  = bn[16+c]*inv - mean*mean;
        float rs   = rsqrtf(var+1e-5f);
        float sc   = g[c]*rs;
        bn[32+c] = sc;
        bn[48+c] = b[c]-mean*sc;
    }
}

__global__ __launch_bounds__(256) void k_xt(const float* __restrict__ x, const float* __restrict__ hcw, float* __restrict__ xt){
    size_t gid = (size_t)blockIdx.x*256 + threadIdx.x;
    int node = (int)(gid>>6); int co = (int)(gid&63);
    int n = node/336, tl = node%336;
    const float* xb = x + (size_t)n*XPERN + tl;
    const float* w  = hcw + co*16;
    float acc=0.f;
    #pragma unroll
    for(int ci=0;ci<16;ci++) acc += xb[ci*336]*w[ci];
    xt[gid]=acc;
}

__global__ __launch_bounds__(256) void k_hist(const int* __restrict__ hi, float* __restrict__ D, float* __restrict__ B){
    int i = blockIdx.x*256+threadIdx.x;
    if(i<EINC){ atomicAdd(D+hi[i],1.f); atomicAdd(B+hi[EINC+i],1.f); }
}

__global__ __launch_bounds__(256) void k_inv(float* __restrict__ D){
    int i = blockIdx.x*256+threadIdx.x;      // covers D then B contiguously
    if(i<2*NODES){ float v=D[i]; D[i] = v>0.f ? 1.f/v : 0.f; }
}

__global__ __launch_bounds__(256) void k_sc1(const int* __restrict__ hi, const float* __restrict__ xt, float* __restrict__ e){
    size_t gid = (size_t)blockIdx.x*256+threadIdx.x;
    int inc = (int)(gid>>6); int c = (int)(gid&63);
    int ni = hi[inc]; int ei = hi[EINC+inc];
    atomicAdd(e + (size_t)ei*64 + c, xt[(size_t)ni*64+c]);
}

__global__ __launch_bounds__(256) void k_sc2(const int* __restrict__ hi, const float* __restrict__ e, const float* __restrict__ Binv, float* __restrict__ h){
    size_t gid = (size_t)blockIdx.x*256+threadIdx.x;
    int inc = (int)(gid>>6); int c = (int)(gid&63);
    int ni = hi[inc]; int ei = hi[EINC+inc];
    atomicAdd(h + (size_t)ni*64 + c, e[(size_t)ei*64+c]*Binv[ei]);
}

// seq[n][o][e] = conv_b[o] + sum_t conv_w[o][t]*(h[n*21504 + 2688k + 42t + u]*Dinv + hc_b),  e=42k+u
__global__ __launch_bounds__(256) void k_seq(const float* __restrict__ h, const float* __restrict__ Dinv,
                                             const float* __restrict__ hcb, const float* __restrict__ cw,
                                             const float* __restrict__ cb, float* __restrict__ seq){
    __shared__ float Ds[336], hb[64], cws[64], cbs[8];
    int n = blockIdx.x, tid=threadIdx.x;
    for(int f=tid; f<336; f+=256) Ds[f]=Dinv[n*336+f];
    if(tid<64){ hb[tid]=hcb[tid]; cws[tid]=cw[tid]; }
    if(tid<8) cbs[tid]=cb[tid];
    __syncthreads();
    const float* hn = h + (size_t)n*PERN;
    for(int e=tid; e<336; e+=256){
        int k = e/42, u = e%42;
        float hv[8];
        #pragma unroll
        for(int t=0;t<8;t++){
            int idx = 2688*k + t*42 + u;
            hv[t] = hn[idx]*Ds[idx>>6] + hb[idx&63];
        }
        #pragma unroll
        for(int o=0;o<8;o++){
            float acc=cbs[o];
            #pragma unroll
            for(int t=0;t<8;t++) acc += cws[o*8+t]*hv[t];
            seq[(size_t)n*2688 + o*336 + e]=acc;
        }
    }
}

__global__ __launch_bounds__(256) void k_fusew(const float* __restrict__ ipw, const float* __restrict__ wq,
                                               const float* __restrict__ wk, const float* __restrict__ wv,
                                               const float* __restrict__ fcw, const float* __restrict__ opw,
                                               float* __restrict__ W){
    int gid = blockIdx.x*256+threadIdx.x;
    float acc=0.f;
    if(gid < 3*112896){
        int m = gid/112896, r = gid%112896, o = r/336, i = r%336;
        const float* A  = ipw + (size_t)(m*336+o)*336;
        const float* Bm = (m==0)?wq:((m==1)?wk:wv);
        for(int k=0;k<336;k++) acc += A[k]*Bm[k*336+i];
    } else {
        int g2 = gid-3*112896; int j=g2/336, i=g2%336;
        const float* A = fcw + (size_t)j*336;
        for(int k=0;k<336;k++) acc += A[k]*opw[k*336+i];
    }
    W[gid]=acc;
}

__global__ __launch_bounds__(256) void k_fuseb(const float* __restrict__ ipw, const float* __restrict__ ipb,
                                               const float* __restrict__ bq, const float* __restrict__ bk,
                                               const float* __restrict__ bv, const float* __restrict__ fcw,
                                               const float* __restrict__ opb, const float* __restrict__ fcb,
                                               float* __restrict__ BE){
    int gid = blockIdx.x*256+threadIdx.x;
    if(gid<1008){
        int m=gid/336;
        const float* A  = ipw + (size_t)gid*336;
        const float* bm = (m==0)?bq:((m==1)?bk:bv);
        float acc=ipb[gid];
        for(int k=0;k<336;k++) acc+=A[k]*bm[k];
        BE[gid]=acc;
    } else if(gid<3696){
        int j=gid-1008;
        const float* A = fcw+(size_t)j*336;
        float acc=fcb[j];
        for(int k=0;k<336;k++) acc+=A[k]*opb[k];
        BE[gid]=acc;
    }
}

__global__ __launch_bounds__(256) void k_attn(const float* __restrict__ seq, const float* __restrict__ W,
                                              const float* __restrict__ BE, float* __restrict__ ao){
    __shared__ float ss[8*336], qs[8*336], ks[8*336], vs[8*336], sc[256];
    int n=blockIdx.x, tid=threadIdx.x;
    for(int f=tid;f<2688;f+=256) ss[f]=seq[(size_t)n*2688+f];
    __syncthreads();
    if(tid<252){
        int m=tid/84, o0=(tid%84)*4;
        float acc[4][8];
        #pragma unroll
        for(int jj=0;jj<4;jj++){
            float b=BE[m*336+o0+jj];
            #pragma unroll
            for(int s=0;s<8;s++) acc[jj][s]=b;
        }
        const float* Wm = W + (size_t)m*112896 + (size_t)o0*336;
        for(int i=0;i<336;i++){
            float a[8];
            #pragma unroll
            for(int s=0;s<8;s++) a[s]=ss[s*336+i];
            #pragma unroll
            for(int jj=0;jj<4;jj++){
                float w=Wm[jj*336+i];
                #pragma unroll
                for(int s=0;s<8;s++) acc[jj][s]+=w*a[s];
            }
        }
        float* dst = (m==0)?qs:((m==1)?ks:vs);
        #pragma unroll
        for(int jj=0;jj<4;jj++)
            #pragma unroll
            for(int s=0;s<8;s++) dst[s*336+o0+jj]=acc[jj][s];
    }
    __syncthreads();
    {   // scores: tid = h*64 + s*8 + t
        int h=tid>>6, s=(tid>>3)&7, t=tid&7;
        float d=0.f;
        for(int k=0;k<84;k++) d += qs[s*336+h*84+k]*ks[t*336+h*84+k];
        sc[tid]=d*0.10910894511799619f;   // 1/sqrt(84)
    }
    __syncthreads();
    if(tid<32){
        float* row = sc + (tid>>3)*64 + (tid&7)*8;
        float m=row[0];
        #pragma unroll
        for(int t=1;t<8;t++) m=fmaxf(m,row[t]);
        float sum=0.f;
        #pragma unroll
        for(int t=0;t<8;t++){ float e=__expf(row[t]-m); row[t]=e; sum+=e; }
        float r=1.f/sum;
        #pragma unroll
        for(int t=0;t<8;t++) row[t]*=r;
    }
    __syncthreads();
    for(int o=tid;o<336;o+=256){
        int h=o/84;
        float acc[8];
        #pragma unroll
        for(int s=0;s<8;s++) acc[s]=0.f;
        #pragma unroll
        for(int t=0;t<8;t++){
            float v=vs[t*336+o];
            #pragma unroll
            for(int s=0;s<8;s++) acc[s]+=sc[h*64+s*8+t]*v;
        }
        #pragma unroll
        for(int s=0;s<8;s++) ao[(size_t)n*2688 + s*336 + o]=acc[s];
    }
}

__global__ __launch_bounds__(256) void k_final(const float* __restrict__ x, const float* __restrict__ ao,
                                               const float* __restrict__ W, const float* __restrict__ BE,
                                               const float* __restrict__ bn, const float* __restrict__ pw,
                                               const float* __restrict__ pb, float* __restrict__ out){
    __shared__ float xp[5376], as[2688], pws[1024], pbs[64], scs[16], shs[16];
    int n=blockIdx.x, tid=threadIdx.x;
    if(tid<16){ scs[tid]=bn[32+tid]; shs[tid]=bn[48+tid]; }
    if(tid<64) pbs[tid]=pb[tid];
    for(int f=tid;f<1024;f+=256) pws[f]=pw[f];
    for(int f=tid;f<2688;f+=256) as[f]=ao[(size_t)n*2688+f];
    __syncthreads();
    const float* xn = x + (size_t)n*XPERN;
    for(int f=tid;f<5376;f+=256){ int ci=f/336; xp[f]=xn[f]*scs[ci]+shs[ci]; }
    __syncthreads();
    const float* Wfc = W + 3*112896;
    const float* bfc = BE + 1008;
    for(int jt=tid; jt<672; jt+=256){
        float acc[4][8];
        #pragma unroll
        for(int jj=0;jj<4;jj++){
            int j=jt+jj*672;
            int co=j&63, w=j>>6;
            float b=bfc[j]+pbs[co];
            #pragma unroll
            for(int s=0;s<8;s++) acc[jj][s]=b;
            #pragma unroll
            for(int ci=0;ci<16;ci++){
                float c=pws[co*16+ci];
                #pragma unroll
                for(int s=0;s<8;s++) acc[jj][s]+=c*xp[ci*336+s*42+w];
            }
        }
        const float* W0=Wfc+(size_t)(jt       )*336;
        const float* W1=Wfc+(size_t)(jt+  672 )*336;
        const float* W2=Wfc+(size_t)(jt+ 1344 )*336;
        const float* W3=Wfc+(size_t)(jt+ 2016 )*336;
        for(int i=0;i<336;i++){
            float a[8];
            #pragma unroll
            for(int s=0;s<8;s++) a[s]=as[s*336+i];
            float w0=W0[i],w1=W1[i],w2=W2[i],w3=W3[i];
            #pragma unroll
            for(int s=0;s<8;s++){
                acc[0][s]+=w0*a[s]; acc[1][s]+=w1*a[s];
                acc[2][s]+=w2*a[s]; acc[3][s]+=w3*a[s];
            }
        }
        #pragma unroll
        for(int jj=0;jj<4;jj++){
            int j=jt+jj*672;
            #pragma unroll
            for(int s=0;s<8;s++) out[(size_t)n*PERN + s*2688 + j] = fmaxf(acc[jj][s],0.f);
        }
    }
}

extern "C" void kernel_launch(void* const* d_in, const int* in_sizes, int n_in,
                              void* d_out, int out_size, void* d_ws, size_t ws_size,
                              hipStream_t stream) {
    const float* x    = (const float*)d_in[0];
    const int*   hi   = (const int*  )d_in[1];
    const float* hcw  = (const float*)d_in[2];
    const float* hcb  = (const float*)d_in[3];
    const float* cw   = (const float*)d_in[4];
    const float* cb   = (const float*)d_in[5];
    const float* bng  = (const float*)d_in[6];
    const float* bnb  = (const float*)d_in[7];
    const float* pw   = (const float*)d_in[8];
    const float* pb   = (const float*)d_in[9];
    const float* wq   = (const float*)d_in[10];
    const float* bq   = (const float*)d_in[11];
    const float* wk   = (const float*)d_in[12];
    const float* bk   = (const float*)d_in[13];
    const float* wv   = (const float*)d_in[14];
    const float* bv   = (const float*)d_in[15];
    const float* ipw  = (const float*)d_in[16];
    const float* ipb  = (const float*)d_in[17];
    const float* opw  = (const float*)d_in[18];
    const float* opb  = (const float*)d_in[19];
    const float* fcw  = (const float*)d_in[20];
    const float* fcb  = (const float*)d_in[21];
    float* ws  = (float*)d_ws;
    float* out = (float*)d_out;

    // zero: e buffer, and [Dinv|Binv|bn] contiguous block
    hipMemsetAsync(ws + O_B, 0, SZ_AB*sizeof(float), stream);
    hipMemsetAsync(ws + O_D, 0, (2*(size_t)NODES+64)*sizeof(float), stream);

    k_bn_stats<<<8192,256,0,stream>>>(x, ws+O_BN);
    k_bn_final<<<1,64,0,stream>>>(ws+O_BN, bng, bnb);
    k_xt<<<172032,256,0,stream>>>(x, hcw, ws+O_A);
    k_hist<<<10752,256,0,stream>>>(hi, ws+O_D, ws+O_Bd);
    k_inv<<<5376,256,0,stream>>>(ws+O_D);
    k_fusew<<<4851,256,0,stream>>>(ipw, wq, wk, wv, fcw, opw, ws+O_W);
    k_fuseb<<<15,256,0,stream>>>(ipw, ipb, bq, bk, bv, fcw, opb, fcb, ws+O_BE);
    k_sc1<<<688128,256,0,stream>>>(hi, ws+O_A, ws+O_B);
    hipMemsetAsync(ws + O_A, 0, SZ_AB*sizeof(float), stream);   // zero h (reuses xt buffer)
    k_sc2<<<688128,256,0,stream>>>(hi, ws+O_B, ws+O_Bd, ws+O_A);
    k_seq<<<2048,256,0,stream>>>(ws+O_A, ws+O_D, hcb, cw, cb, ws+O_SEQ);
    k_attn<<<2048,256,0,stream>>>(ws+O_SEQ, ws+O_W, ws+O_BE, ws+O_AO);
    k_final<<<2048,256,0,stream>>>(x, ws+O_AO, ws+O_W, ws+O_BE, ws+O_BN, pw, pb, out);
}

// Round 2
// 2976.325 us; speedup vs baseline: 1.7487x; 1.7487x over previous
//
#include <hip/hip_runtime.h>

#define N_    2048
#define CIN   16
#define T_    8
#define VM_   42
#define COUT  64
#define NODES (N_*T_*VM_)        // 688128
#define EINC  (4*NODES)          // 2752512
#define EMB   336
#define PERN  (T_*VM_*COUT)      // 21504
#define XPERN (CIN*T_*VM_)       // 5376

typedef __attribute__((ext_vector_type(8))) short bf16x8;
typedef __attribute__((ext_vector_type(4))) float f32x4;

// ---- ws layout (floats) ----
static const size_t O_A   = 0;                       // xt -> h -> res  (44,040,192 f)
static const size_t SZ_AB = (size_t)NODES*64;
static const size_t O_B   = SZ_AB;                   // e raw -> frag/qkv pool
static const size_t O_SEQ = 2*SZ_AB;                 // seq f32 (5,505,024)
static const size_t SZ_SEQ= (size_t)N_*8*EMB;
static const size_t O_AO  = O_SEQ+SZ_SEQ;            // (spare)
static const size_t O_D   = O_AO+SZ_SEQ;             // Dinv (688,128)
static const size_t O_Bd  = O_D+NODES;               // Binv (688,128)
static const size_t O_BN  = O_Bd+NODES;              // bn stats/scale (64)
static const size_t O_W   = O_BN+64;                 // Wqkv_eff (338688) + Wfc_eff (903168)
static const size_t O_BE  = O_W + 3*EMB*EMB + (size_t)8*EMB*EMB;  // 1008 qkv bias + 2688 fc bias
// sub-pool inside O_B (valid after e is dead):
static const size_t O_SEQF = O_B;                // bf16 frags seq: 1024*5632 sh = 2,883,584 f
static const size_t O_W1F  = O_B + 2900000;      // 63*5632 sh = 177,408 f
static const size_t O_W2F  = O_B + 3100000;      // 168*5632 sh = 473,088 f
static const size_t O_AOF  = O_B + 3600000;      // 1024*5632 sh = 2,883,584 f
static const size_t O_QKV  = O_B + 6600000;      // 16384*1008 f = 16,515,072 f

__device__ inline short bf16r(float f){
    unsigned u = __builtin_bit_cast(unsigned, f);
    u += 0x7FFFu + ((u>>16)&1u);
    return (short)(u>>16);
}

__global__ __launch_bounds__(256) void k_bn_stats(const float* __restrict__ x, float* __restrict__ bn){
    int row  = blockIdx.x*4 + (threadIdx.x>>6);
    int lane = threadIdx.x & 63;
    const float* base = x + (size_t)(row>>4)*XPERN + (size_t)(row&15)*EMB;
    float s=0.f, q=0.f;
    for(int k=lane;k<EMB;k+=64){ float v=base[k]; s+=v; q+=v*v; }
    for(int off=32;off;off>>=1){ s+=__shfl_down(s,off); q+=__shfl_down(q,off); }
    if(lane==0){ atomicAdd(bn+(row&15), s); atomicAdd(bn+16+(row&15), q); }
}

__global__ void k_bn_final(float* bn, const float* __restrict__ g, const float* __restrict__ b){
    int c = threadIdx.x;
    if(c<16){
        const float inv = 1.f/(float)NODES;
        float mean = bn[c]*inv;
        float var  = bn[16+c]*inv - mean*mean;
        float rs   = rsqrtf(var+1e-5f);
        float sc   = g[c]*rs;
        bn[32+c] = sc;
        bn[48+c] = b[c]-mean*sc;
    }
}

__global__ __launch_bounds__(256) void k_xt(const float* __restrict__ x, const float* __restrict__ hcw, float* __restrict__ xt){
    size_t gid = (size_t)blockIdx.x*256 + threadIdx.x;
    int node = (int)(gid>>6); int co = (int)(gid&63);
    int n = node/336, tl = node%336;
    const float* xb = x + (size_t)n*XPERN + tl;
    const float* w  = hcw + co*16;
    float acc=0.f;
    #pragma unroll
    for(int ci=0;ci<16;ci++) acc += xb[ci*336]*w[ci];
    xt[gid]=acc;
}

__global__ __launch_bounds__(256) void k_hist(const int* __restrict__ hi, float* __restrict__ D, float* __restrict__ B){
    int i = blockIdx.x*256+threadIdx.x;
    if(i<EINC){ atomicAdd(D+hi[i],1.f); atomicAdd(B+hi[EINC+i],1.f); }
}

__global__ __launch_bounds__(256) void k_inv(float* __restrict__ D){
    int i = blockIdx.x*256+threadIdx.x;
    if(i<2*NODES){ float v=D[i]; D[i] = v>0.f ? 1.f/v : 0.f; }
}

__global__ __launch_bounds__(256) void k_sc1(const int* __restrict__ hi, const float* __restrict__ xt, float* __restrict__ e){
    size_t gid = (size_t)blockIdx.x*256+threadIdx.x;
    int inc = (int)(gid>>6); int c = (int)(gid&63);
    int ni = hi[inc]; int ei = hi[EINC+inc];
    atomicAdd(e + (size_t)ei*64 + c, xt[(size_t)ni*64+c]);
}

__global__ __launch_bounds__(256) void k_sc2(const int* __restrict__ hi, const float* __restrict__ e, const float* __restrict__ Binv, float* __restrict__ h){
    size_t gid = (size_t)blockIdx.x*256+threadIdx.x;
    int inc = (int)(gid>>6); int c = (int)(gid&63);
    int ni = hi[inc]; int ei = hi[EINC+inc];
    atomicAdd(h + (size_t)ni*64 + c, e[(size_t)ei*64+c]*Binv[ei]);
}

__global__ __launch_bounds__(256) void k_seq(const float* __restrict__ h, const float* __restrict__ Dinv,
                                             const float* __restrict__ hcb, const float* __restrict__ cw,
                                             const float* __restrict__ cb, float* __restrict__ seq){
    __shared__ float Ds[336], hb[64], cws[64], cbs[8];
    int n = blockIdx.x, tid=threadIdx.x;
    for(int f=tid; f<336; f+=256) Ds[f]=Dinv[n*336+f];
    if(tid<64){ hb[tid]=hcb[tid]; cws[tid]=cw[tid]; }
    if(tid<8) cbs[tid]=cb[tid];
    __syncthreads();
    const float* hn = h + (size_t)n*PERN;
    for(int e=tid; e<336; e+=256){
        int k = e/42, u = e%42;
        float hv[8];
        #pragma unroll
        for(int t=0;t<8;t++){
            int idx = 2688*k + t*42 + u;
            hv[t] = hn[idx]*Ds[idx>>6] + hb[idx&63];
        }
        #pragma unroll
        for(int o=0;o<8;o++){
            float acc=cbs[o];
            #pragma unroll
            for(int t=0;t<8;t++) acc += cws[o*8+t]*hv[t];
            seq[(size_t)n*2688 + o*336 + e]=acc;
        }
    }
}

__global__ __launch_bounds__(256) void k_fusew(const float* __restrict__ ipw, const float* __restrict__ wq,
                                               const float* __restrict__ wk, const float* __restrict__ wv,
                                               const float* __restrict__ fcw, const float* __restrict__ opw,
                                               float* __restrict__ W){
    int gid = blockIdx.x*256+threadIdx.x;
    float acc=0.f;
    if(gid < 3*112896){
        int m = gid/112896, r = gid%112896, o = r/336, i = r%336;
        const float* A  = ipw + (size_t)(m*336+o)*336;
        const float* Bm = (m==0)?wq:((m==1)?wk:wv);
        for(int k=0;k<336;k++) acc += A[k]*Bm[k*336+i];
    } else {
        int g2 = gid-3*112896; int j=g2/336, i=g2%336;
        const float* A = fcw + (size_t)j*336;
        for(int k=0;k<336;k++) acc += A[k]*opw[k*336+i];
    }
    W[gid]=acc;
}

__global__ __launch_bounds__(256) void k_fuseb(const float* __restrict__ ipw, const float* __restrict__ ipb,
                                               const float* __restrict__ bq, const float* __restrict__ bk,
                                               const float* __restrict__ bv, const float* __restrict__ fcw,
                                               const float* __restrict__ opb, const float* __restrict__ fcb,
                                               float* __restrict__ BE){
    int gid = blockIdx.x*256+threadIdx.x;
    if(gid<1008){
        int m=gid/336;
        const float* A  = ipw + (size_t)gid*336;
        const float* bm = (m==0)?bq:((m==1)?bk:bv);
        float acc=ipb[gid];
        for(int k=0;k<336;k++) acc+=A[k]*bm[k];
        BE[gid]=acc;
    } else if(gid<3696){
        int j=gid-1008;
        const float* A = fcw+(size_t)j*336;
        float acc=fcb[j];
        for(int k=0;k<336;k++) acc+=A[k]*opb[k];
        BE[gid]=acc;
    }
}

// residual + all fc-path biases: res[r=n*8+s][j] = bfc[j] + pb[co] + sum_ci pw[co,ci]*xbn[n,ci,s,w]
__global__ __launch_bounds__(256) void k_res(const float* __restrict__ x, const float* __restrict__ bn,
                                             const float* __restrict__ pw, const float* __restrict__ pb,
                                             const float* __restrict__ bfc, float* __restrict__ res){
    __shared__ float xp[5376], pws[1024], pbs[64], scs[16], shs[16];
    int n=blockIdx.x, tid=threadIdx.x;
    if(tid<16){ scs[tid]=bn[32+tid]; shs[tid]=bn[48+tid]; }
    if(tid<64) pbs[tid]=pb[tid];
    for(int f=tid;f<1024;f+=256) pws[f]=pw[f];
    __syncthreads();
    const float* xn = x + (size_t)n*XPERN;
    for(int f=tid;f<5376;f+=256){ int ci=f/336; xp[f]=xn[f]*scs[ci]+shs[ci]; }
    __syncthreads();
    float* rn = res + (size_t)n*PERN;
    for(int j=tid;j<2688;j+=256){
        int co=j&63, w=j>>6;
        float base = bfc[j]+pbs[co];
        float a[8];
        #pragma unroll
        for(int s=0;s<8;s++) a[s]=base;
        #pragma unroll
        for(int ci=0;ci<16;ci++){
            float c=pws[co*16+ci];
            const float* xr = xp + ci*336 + w;
            #pragma unroll
            for(int s=0;s<8;s++) a[s]+=c*xr[s*42];
        }
        #pragma unroll
        for(int s=0;s<8;s++) rn[s*2688+j]=a[s];
    }
}

// f32 [rt*16+row][336] row-major -> bf16 MFMA fragments [rt][kb=11][lane][8], K padded to 352
__global__ __launch_bounds__(256) void k_frag(const float* __restrict__ src, short* __restrict__ dst){
    int rt=blockIdx.x, tid=threadIdx.x;
    const float* s0 = src + (size_t)rt*16*336;
    short* d0 = dst + (size_t)rt*5632;
    for(int idx=tid; idx<5632; idx+=256){
        int kb=idx>>9, rem=idx&511, l=rem>>3, j=rem&7;
        int row=l&15, k=kb*32+((l>>4)<<3)+j;
        float v = (k<336)? s0[row*336+k] : 0.f;
        d0[idx]=bf16r(v);
    }
}

// C[r][col] = sum_k A[r][k]*W[col][k] (+bias[col]) (+addterm) (relu)
// grid: (R/32, ceil(CT/4)); 4 waves, wave -> 1 col tile, 2 row tiles
__global__ __launch_bounds__(256) void k_gemm(const bf16x8* __restrict__ Af, const bf16x8* __restrict__ Wf,
                                              const float* __restrict__ addterm, const float* __restrict__ bias,
                                              float* __restrict__ C, int CT, int CW, int relu){
    int wv = threadIdx.x>>6, l = threadIdx.x&63;
    int ct = blockIdx.y*4 + wv;
    if(ct>=CT) return;
    int rt0 = blockIdx.x*2;
    const bf16x8* Ap = Af + (size_t)rt0*704 + l;
    const bf16x8* Bp = Wf + (size_t)ct *704 + l;
    f32x4 acc0={0.f,0.f,0.f,0.f}, acc1={0.f,0.f,0.f,0.f};
    #pragma unroll
    for(int kb=0;kb<11;kb++){
        bf16x8 b  = Bp[kb*64];
        bf16x8 a0 = Ap[kb*64];
        bf16x8 a1 = Ap[704 + kb*64];
        acc0 = __builtin_amdgcn_mfma_f32_16x16x32_bf16(a0,b,acc0,0,0,0);
        acc1 = __builtin_amdgcn_mfma_f32_16x16x32_bf16(a1,b,acc1,0,0,0);
    }
    int col = ct*16 + (l&15);
    int r   = rt0*16 + (l>>4)*4;
    float bb = bias ? bias[col] : 0.f;
    #pragma unroll
    for(int rr=0;rr<4;rr++){
        size_t o0 = (size_t)(r+rr)*CW + col;
        size_t o1 = (size_t)(r+16+rr)*CW + col;
        float v0 = acc0[rr] + bb;
        float v1 = acc1[rr] + bb;
        if(addterm){ v0 += addterm[o0]; v1 += addterm[o1]; }
        if(relu){ v0 = fmaxf(v0,0.f); v1 = fmaxf(v1,0.f); }
        C[o0]=v0; C[o1]=v1;
    }
}

// per-n attention on fused qkv rows [n*8..n*8+7][1008]; emits ao directly as bf16 fragments
__global__ __launch_bounds__(256) void k_attn2(const float* __restrict__ qkv, short* __restrict__ aof){
    __shared__ float ss[8*1008];
    __shared__ float sc[256];
    __shared__ float aos[8*336];
    int n=blockIdx.x, tid=threadIdx.x;
    const float* src = qkv + (size_t)n*8064;
    for(int f=tid; f<8064; f+=256) ss[f]=src[f];
    __syncthreads();
    {
        int h=tid>>6, s=(tid>>3)&7, t=tid&7;
        const float* qp=ss + s*1008 + h*84;
        const float* kp=ss + t*1008 + 336 + h*84;
        float d=0.f;
        for(int d0=0;d0<84;d0++) d+=qp[d0]*kp[d0];
        sc[tid]=d*0.10910894511799619f;
    }
    __syncthreads();
    if(tid<32){
        float* row = sc + (tid>>3)*64 + (tid&7)*8;
        float m=row[0];
        #pragma unroll
        for(int t=1;t<8;t++) m=fmaxf(m,row[t]);
        float sum=0.f;
        #pragma unroll
        for(int t=0;t<8;t++){ float e=__expf(row[t]-m); row[t]=e; sum+=e; }
        float r=1.f/sum;
        #pragma unroll
        for(int t=0;t<8;t++) row[t]*=r;
    }
    __syncthreads();
    for(int o=tid;o<336;o+=256){
        int h=o/84;
        float acc[8];
        #pragma unroll
        for(int s=0;s<8;s++) acc[s]=0.f;
        #pragma unroll
        for(int t=0;t<8;t++){
            float v=ss[t*1008+672+o];
            #pragma unroll
            for(int s=0;s<8;s++) acc[s]+=sc[h*64+s*8+t]*v;
        }
        #pragma unroll
        for(int s=0;s<8;s++) aos[s*336+o]=acc[s];
    }
    __syncthreads();
    int rt=n>>1, half=n&1;
    for(int e=tid; e<2816; e+=256){
        int row=e&7, k=e>>3;
        float v = (k<336)? aos[row*336+k] : 0.f;
        int l = (half*8+row) | (((k>>3)&3)<<4);
        int j = k&7;
        aof[(size_t)rt*5632 + (size_t)(k>>5)*512 + l*8 + j] = bf16r(v);
    }
}

extern "C" void kernel_launch(void* const* d_in, const int* in_sizes, int n_in,
                              void* d_out, int out_size, void* d_ws, size_t ws_size,
                              hipStream_t stream) {
    const float* x    = (const float*)d_in[0];
    const int*   hi   = (const int*  )d_in[1];
    const float* hcw  = (const float*)d_in[2];
    const float* hcb  = (const float*)d_in[3];
    const float* cw   = (const float*)d_in[4];
    const float* cb   = (const float*)d_in[5];
    const float* bng  = (const float*)d_in[6];
    const float* bnb  = (const float*)d_in[7];
    const float* pw   = (const float*)d_in[8];
    const float* pb   = (const float*)d_in[9];
    const float* wq   = (const float*)d_in[10];
    const float* bq   = (const float*)d_in[11];
    const float* wk   = (const float*)d_in[12];
    const float* bk   = (const float*)d_in[13];
    const float* wv   = (const float*)d_in[14];
    const float* bv   = (const float*)d_in[15];
    const float* ipw  = (const float*)d_in[16];
    const float* ipb  = (const float*)d_in[17];
    const float* opw  = (const float*)d_in[18];
    const float* opb  = (const float*)d_in[19];
    const float* fcw  = (const float*)d_in[20];
    const float* fcb  = (const float*)d_in[21];
    float* ws  = (float*)d_ws;
    float* out = (float*)d_out;

    hipMemsetAsync(ws + O_B, 0, SZ_AB*sizeof(float), stream);                    // e
    hipMemsetAsync(ws + O_D, 0, (2*(size_t)NODES+64)*sizeof(float), stream);     // D,B,bn

    k_bn_stats<<<8192,256,0,stream>>>(x, ws+O_BN);
    k_bn_final<<<1,64,0,stream>>>(ws+O_BN, bng, bnb);
    k_xt<<<172032,256,0,stream>>>(x, hcw, ws+O_A);
    k_hist<<<10752,256,0,stream>>>(hi, ws+O_D, ws+O_Bd);
    k_inv<<<5376,256,0,stream>>>(ws+O_D);
    k_fusew<<<4851,256,0,stream>>>(ipw, wq, wk, wv, fcw, opw, ws+O_W);
    k_fuseb<<<15,256,0,stream>>>(ipw, ipb, bq, bk, bv, fcw, opb, fcb, ws+O_BE);
    k_sc1<<<688128,256,0,stream>>>(hi, ws+O_A, ws+O_B);
    hipMemsetAsync(ws + O_A, 0, SZ_AB*sizeof(float), stream);                    // h
    k_sc2<<<688128,256,0,stream>>>(hi, ws+O_B, ws+O_Bd, ws+O_A);
    k_seq<<<2048,256,0,stream>>>(ws+O_A, ws+O_D, hcb, cw, cb, ws+O_SEQ);
    // h and e now dead: O_A becomes res, O_B becomes frag/qkv pool
    k_res<<<2048,256,0,stream>>>(x, ws+O_BN, pw, pb, ws+O_BE+1008, ws+O_A);
    k_frag<<<1024,256,0,stream>>>(ws+O_SEQ,            (short*)(ws+O_SEQF));
    k_frag<<<  63,256,0,stream>>>(ws+O_W,              (short*)(ws+O_W1F));
    k_frag<<< 168,256,0,stream>>>(ws+O_W+3*112896,     (short*)(ws+O_W2F));
    {   dim3 g1(512,16);
        k_gemm<<<g1,256,0,stream>>>((const bf16x8*)(ws+O_SEQF),(const bf16x8*)(ws+O_W1F),
                                    nullptr, ws+O_BE, ws+O_QKV, 63, 1008, 0); }
    k_attn2<<<2048,256,0,stream>>>(ws+O_QKV, (short*)(ws+O_AOF));
    {   dim3 g2(512,42);
        k_gemm<<<g2,256,0,stream>>>((const bf16x8*)(ws+O_AOF),(const bf16x8*)(ws+O_W2F),
                                    ws+O_A, nullptr, out, 168, 2688, 1); }
}

// Round 3
// 2603.201 us; speedup vs baseline: 1.9993x; 1.1433x over previous
//
#include <hip/hip_runtime.h>

#define N_    2048
#define CIN   16
#define T_    8
#define VM_   42
#define COUT  64
#define NODES (N_*T_*VM_)        // 688128
#define EINC  (4*NODES)          // 2752512
#define EMB   336
#define PERN  (T_*VM_*COUT)      // 21504
#define XPERN (CIN*T_*VM_)       // 5376

typedef __attribute__((ext_vector_type(8))) short bf16x8;
typedef __attribute__((ext_vector_type(4))) float f32x4;

// ---- ws layout (floats) ----
static const size_t O_A   = 0;                       // xt -> h -> res  (44,040,192 f)
static const size_t SZ_AB = (size_t)NODES*64;
static const size_t O_B   = SZ_AB;                   // e -> frag/qkv pool
static const size_t O_SEQ = 2*SZ_AB;                 // seq f32 (5,505,024)
static const size_t SZ_SEQ= (size_t)N_*8*EMB;
static const size_t O_AO  = O_SEQ+SZ_SEQ;            // CSR int pool (5,505,024 f = 22MB)
static const size_t O_D   = O_AO+SZ_SEQ;             // (unused now)
static const size_t O_Bd  = O_D+NODES;               // (unused now)
static const size_t O_BN  = O_Bd+NODES;              // bn stats/scale (64)
static const size_t O_W   = O_BN+64;                 // Wqkv_eff + Wfc_eff
static const size_t O_BE  = O_W + 3*EMB*EMB + (size_t)8*EMB*EMB;  // fused biases
// sub-pool inside O_B (valid after e is dead):
static const size_t O_SEQF = O_B;
static const size_t O_W1F  = O_B + 2900000;
static const size_t O_W2F  = O_B + 3100000;
static const size_t O_AOF  = O_B + 3600000;
static const size_t O_QKV  = O_B + 6600000;
// ---- int pool (offsets in ints, relative to (int*)(ws+O_AO)) ----
#define I_CNTD 0
#define I_CNTB 688128
#define I_CURS 1376256           // 2 cursors (pad 64)
#define I_CUR  1376320
#define I_CSR  2064448           // 2,752,512 entries -> end 4,816,960 < 5,505,024

__device__ inline short bf16r(float f){
    unsigned u = __builtin_bit_cast(unsigned, f);
    u += 0x7FFFu + ((u>>16)&1u);
    return (short)(u>>16);
}

__global__ __launch_bounds__(256) void k_bn_stats(const float* __restrict__ x, float* __restrict__ bn){
    int row  = blockIdx.x*4 + (threadIdx.x>>6);
    int lane = threadIdx.x & 63;
    const float* base = x + (size_t)(row>>4)*XPERN + (size_t)(row&15)*EMB;
    float s=0.f, q=0.f;
    for(int k=lane;k<EMB;k+=64){ float v=base[k]; s+=v; q+=v*v; }
    for(int off=32;off;off>>=1){ s+=__shfl_down(s,off); q+=__shfl_down(q,off); }
    if(lane==0){ atomicAdd(bn+(row&15), s); atomicAdd(bn+16+(row&15), q); }
}

__global__ void k_bn_final(float* bn, const float* __restrict__ g, const float* __restrict__ b){
    int c = threadIdx.x;
    if(c<16){
        const float inv = 1.f/(float)NODES;
        float mean = bn[c]*inv;
        float var  = bn[16+c]*inv - mean*mean;
        float rs   = rsqrtf(var+1e-5f);
        float sc   = g[c]*rs;
        bn[32+c] = sc;
        bn[48+c] = b[c]-mean*sc;
    }
}

__global__ __launch_bounds__(256) void k_xt(const float* __restrict__ x, const float* __restrict__ hcw, float* __restrict__ xt){
    size_t gid = (size_t)blockIdx.x*256 + threadIdx.x;
    int node = (int)(gid>>6); int co = (int)(gid&63);
    int n = node/336, tl = node%336;
    const float* xb = x + (size_t)n*XPERN + tl;
    const float* w  = hcw + co*16;
    float acc=0.f;
    #pragma unroll
    for(int ci=0;ci<16;ci++) acc += xb[ci*336]*w[ci];
    xt[gid]=acc;
}

__global__ __launch_bounds__(256) void k_hist(const int* __restrict__ hi, int* __restrict__ cntD, int* __restrict__ cntB){
    int i = blockIdx.x*256+threadIdx.x;
    if(i<EINC){ atomicAdd(cntD+hi[i],1); atomicAdd(cntB+hi[EINC+i],1); }
}

// block-aggregated bump allocation: cur[v] = global base for segment v
__global__ __launch_bounds__(1024) void k_alloc(const int* __restrict__ cnt, int* __restrict__ cur, int* __restrict__ cursor){
    __shared__ int wtot[16], woff[16], bbase;
    int gid = blockIdx.x*1024 + threadIdx.x;
    int w = threadIdx.x>>6, lane = threadIdx.x&63;
    int orig = cnt[gid];
    int incl = orig;
    #pragma unroll
    for(int off=1;off<64;off<<=1){
        int nv = __shfl_up(incl, off);
        if(lane>=off) incl += nv;
    }
    if(lane==63) wtot[w]=incl;
    __syncthreads();
    if(threadIdx.x==0){
        int run=0;
        #pragma unroll
        for(int i=0;i<16;i++){ woff[i]=run; run+=wtot[i]; }
        bbase = atomicAdd(cursor, run);
    }
    __syncthreads();
    cur[gid] = bbase + woff[w] + (incl - orig);
}

// scatter incidences into unordered CSR: csr grouped by seg[], payload pay[]
__global__ __launch_bounds__(256) void k_fill(const int* __restrict__ seg, const int* __restrict__ pay,
                                              int* __restrict__ cur, int* __restrict__ csr){
    int i = blockIdx.x*256+threadIdx.x;
    if(i<EINC){
        int p = atomicAdd(cur+seg[i], 1);
        csr[p] = pay[i];
    }
}

// dst[s*64+lane] = (1/cnt[s]) * sum_j src[csr[j]*64+lane]   (after fill, cur[s] = end of segment)
__global__ __launch_bounds__(256) void k_gath(const float* __restrict__ src, const int* __restrict__ csr,
                                              const int* __restrict__ cur, const int* __restrict__ cnt,
                                              float* __restrict__ dst){
    int s = blockIdx.x*4 + (threadIdx.x>>6);
    int lane = threadIdx.x & 63;
    int c = cnt[s];
    int end = cur[s];
    int start = end - c;
    float acc = 0.f;
    int nv = (c<64)? c : 64;
    int myidx = (lane<nv)? csr[start+lane] : 0;
    for(int j=0;j<nv;j++){
        int idx = __shfl(myidx, j);
        acc += src[(size_t)idx*64 + lane];
    }
    for(int j=64;j<c;j++){              // practically never (Poisson mean 4)
        int idx = csr[start+j];
        acc += src[(size_t)idx*64 + lane];
    }
    float scale = (c>0)? 1.f/(float)c : 0.f;
    dst[(size_t)s*64 + lane] = acc*scale;
}

// seq[n][o][e] = cb[o] + sum_t cw[o][t]*(h[2688k+42t+u] + hcb)   (h already Dinv-scaled)
__global__ __launch_bounds__(256) void k_seq(const float* __restrict__ h,
                                             const float* __restrict__ hcb, const float* __restrict__ cw,
                                             const float* __restrict__ cb, float* __restrict__ seq){
    __shared__ float hb[64], cws[64], cbs[8];
    int n = blockIdx.x, tid=threadIdx.x;
    if(tid<64){ hb[tid]=hcb[tid]; cws[tid]=cw[tid]; }
    if(tid<8) cbs[tid]=cb[tid];
    __syncthreads();
    const float* hn = h + (size_t)n*PERN;
    for(int e=tid; e<336; e+=256){
        int k = e/42, u = e%42;
        float hv[8];
        #pragma unroll
        for(int t=0;t<8;t++){
            int idx = 2688*k + t*42 + u;
            hv[t] = hn[idx] + hb[idx&63];
        }
        #pragma unroll
        for(int o=0;o<8;o++){
            float acc=cbs[o];
            #pragma unroll
            for(int t=0;t<8;t++) acc += cws[o*8+t]*hv[t];
            seq[(size_t)n*2688 + o*336 + e]=acc;
        }
    }
}

__global__ __launch_bounds__(256) void k_fusew(const float* __restrict__ ipw, const float* __restrict__ wq,
                                               const float* __restrict__ wk, const float* __restrict__ wv,
                                               const float* __restrict__ fcw, const float* __restrict__ opw,
                                               float* __restrict__ W){
    int gid = blockIdx.x*256+threadIdx.x;
    float acc=0.f;
    if(gid < 3*112896){
        int m = gid/112896, r = gid%112896, o = r/336, i = r%336;
        const float* A  = ipw + (size_t)(m*336+o)*336;
        const float* Bm = (m==0)?wq:((m==1)?wk:wv);
        for(int k=0;k<336;k++) acc += A[k]*Bm[k*336+i];
    } else {
        int g2 = gid-3*112896; int j=g2/336, i=g2%336;
        const float* A = fcw + (size_t)j*336;
        for(int k=0;k<336;k++) acc += A[k]*opw[k*336+i];
    }
    W[gid]=acc;
}

__global__ __launch_bounds__(256) void k_fuseb(const float* __restrict__ ipw, const float* __restrict__ ipb,
                                               const float* __restrict__ bq, const float* __restrict__ bk,
                                               const float* __restrict__ bv, const float* __restrict__ fcw,
                                               const float* __restrict__ opb, const float* __restrict__ fcb,
                                               float* __restrict__ BE){
    int gid = blockIdx.x*256+threadIdx.x;
    if(gid<1008){
        int m=gid/336;
        const float* A  = ipw + (size_t)gid*336;
        const float* bm = (m==0)?bq:((m==1)?bk:bv);
        float acc=ipb[gid];
        for(int k=0;k<336;k++) acc+=A[k]*bm[k];
        BE[gid]=acc;
    } else if(gid<3696){
        int j=gid-1008;
        const float* A = fcw+(size_t)j*336;
        float acc=fcb[j];
        for(int k=0;k<336;k++) acc+=A[k]*opb[k];
        BE[gid]=acc;
    }
}

__global__ __launch_bounds__(256) void k_res(const float* __restrict__ x, const float* __restrict__ bn,
                                             const float* __restrict__ pw, const float* __restrict__ pb,
                                             const float* __restrict__ bfc, float* __restrict__ res){
    __shared__ float xp[5376], pws[1024], pbs[64], scs[16], shs[16];
    int n=blockIdx.x, tid=threadIdx.x;
    if(tid<16){ scs[tid]=bn[32+tid]; shs[tid]=bn[48+tid]; }
    if(tid<64) pbs[tid]=pb[tid];
    for(int f=tid;f<1024;f+=256) pws[f]=pw[f];
    __syncthreads();
    const float* xn = x + (size_t)n*XPERN;
    for(int f=tid;f<5376;f+=256){ int ci=f/336; xp[f]=xn[f]*scs[ci]+shs[ci]; }
    __syncthreads();
    float* rn = res + (size_t)n*PERN;
    for(int j=tid;j<2688;j+=256){
        int co=j&63, w=j>>6;
        float base = bfc[j]+pbs[co];
        float a[8];
        #pragma unroll
        for(int s=0;s<8;s++) a[s]=base;
        #pragma unroll
        for(int ci=0;ci<16;ci++){
            float c=pws[co*16+ci];
            const float* xr = xp + ci*336 + w;
            #pragma unroll
            for(int s=0;s<8;s++) a[s]+=c*xr[s*42];
        }
        #pragma unroll
        for(int s=0;s<8;s++) rn[s*2688+j]=a[s];
    }
}

__global__ __launch_bounds__(256) void k_frag(const float* __restrict__ src, short* __restrict__ dst){
    int rt=blockIdx.x, tid=threadIdx.x;
    const float* s0 = src + (size_t)rt*16*336;
    short* d0 = dst + (size_t)rt*5632;
    for(int idx=tid; idx<5632; idx+=256){
        int kb=idx>>9, rem=idx&511, l=rem>>3, j=rem&7;
        int row=l&15, k=kb*32+((l>>4)<<3)+j;
        float v = (k<336)? s0[row*336+k] : 0.f;
        d0[idx]=bf16r(v);
    }
}

__global__ __launch_bounds__(256) void k_gemm(const bf16x8* __restrict__ Af, const bf16x8* __restrict__ Wf,
                                              const float* __restrict__ addterm, const float* __restrict__ bias,
                                              float* __restrict__ C, int CT, int CW, int relu){
    int wv = threadIdx.x>>6, l = threadIdx.x&63;
    int ct = blockIdx.y*4 + wv;
    if(ct>=CT) return;
    int rt0 = blockIdx.x*2;
    const bf16x8* Ap = Af + (size_t)rt0*704 + l;
    const bf16x8* Bp = Wf + (size_t)ct *704 + l;
    f32x4 acc0={0.f,0.f,0.f,0.f}, acc1={0.f,0.f,0.f,0.f};
    #pragma unroll
    for(int kb=0;kb<11;kb++){
        bf16x8 b  = Bp[kb*64];
        bf16x8 a0 = Ap[kb*64];
        bf16x8 a1 = Ap[704 + kb*64];
        acc0 = __builtin_amdgcn_mfma_f32_16x16x32_bf16(a0,b,acc0,0,0,0);
        acc1 = __builtin_amdgcn_mfma_f32_16x16x32_bf16(a1,b,acc1,0,0,0);
    }
    int col = ct*16 + (l&15);
    int r   = rt0*16 + (l>>4)*4;
    float bb = bias ? bias[col] : 0.f;
    #pragma unroll
    for(int rr=0;rr<4;rr++){
        size_t o0 = (size_t)(r+rr)*CW + col;
        size_t o1 = (size_t)(r+16+rr)*CW + col;
        float v0 = acc0[rr] + bb;
        float v1 = acc1[rr] + bb;
        if(addterm){ v0 += addterm[o0]; v1 += addterm[o1]; }
        if(relu){ v0 = fmaxf(v0,0.f); v1 = fmaxf(v1,0.f); }
        C[o0]=v0; C[o1]=v1;
    }
}

__global__ __launch_bounds__(256) void k_attn2(const float* __restrict__ qkv, short* __restrict__ aof){
    __shared__ float ss[8*1008];
    __shared__ float sc[256];
    __shared__ float aos[8*336];
    int n=blockIdx.x, tid=threadIdx.x;
    const float* src = qkv + (size_t)n*8064;
    for(int f=tid; f<8064; f+=256) ss[f]=src[f];
    __syncthreads();
    {
        int h=tid>>6, s=(tid>>3)&7, t=tid&7;
        const float* qp=ss + s*1008 + h*84;
        const float* kp=ss + t*1008 + 336 + h*84;
        float d=0.f;
        for(int d0=0;d0<84;d0++) d+=qp[d0]*kp[d0];
        sc[tid]=d*0.10910894511799619f;
    }
    __syncthreads();
    if(tid<32){
        float* row = sc + (tid>>3)*64 + (tid&7)*8;
        float m=row[0];
        #pragma unroll
        for(int t=1;t<8;t++) m=fmaxf(m,row[t]);
        float sum=0.f;
        #pragma unroll
        for(int t=0;t<8;t++){ float e=__expf(row[t]-m); row[t]=e; sum+=e; }
        float r=1.f/sum;
        #pragma unroll
        for(int t=0;t<8;t++) row[t]*=r;
    }
    __syncthreads();
    for(int o=tid;o<336;o+=256){
        int h=o/84;
        float acc[8];
        #pragma unroll
        for(int s=0;s<8;s++) acc[s]=0.f;
        #pragma unroll
        for(int t=0;t<8;t++){
            float v=ss[t*1008+672+o];
            #pragma unroll
            for(int s=0;s<8;s++) acc[s]+=sc[h*64+s*8+t]*v;
        }
        #pragma unroll
        for(int s=0;s<8;s++) aos[s*336+o]=acc[s];
    }
    __syncthreads();
    int rt=n>>1, half=n&1;
    for(int e=tid; e<2816; e+=256){
        int row=e&7, k=e>>3;
        float v = (k<336)? aos[row*336+k] : 0.f;
        int l = (half*8+row) | (((k>>3)&3)<<4);
        int j = k&7;
        aof[(size_t)rt*5632 + (size_t)(k>>5)*512 + l*8 + j] = bf16r(v);
    }
}

extern "C" void kernel_launch(void* const* d_in, const int* in_sizes, int n_in,
                              void* d_out, int out_size, void* d_ws, size_t ws_size,
                              hipStream_t stream) {
    const float* x    = (const float*)d_in[0];
    const int*   hi   = (const int*  )d_in[1];
    const float* hcw  = (const float*)d_in[2];
    const float* hcb  = (const float*)d_in[3];
    const float* cw   = (const float*)d_in[4];
    const float* cb   = (const float*)d_in[5];
    const float* bng  = (const float*)d_in[6];
    const float* bnb  = (const float*)d_in[7];
    const float* pw   = (const float*)d_in[8];
    const float* pb   = (const float*)d_in[9];
    const float* wq   = (const float*)d_in[10];
    const float* bq   = (const float*)d_in[11];
    const float* wk   = (const float*)d_in[12];
    const float* bk   = (const float*)d_in[13];
    const float* wv   = (const float*)d_in[14];
    const float* bv   = (const float*)d_in[15];
    const float* ipw  = (const float*)d_in[16];
    const float* ipb  = (const float*)d_in[17];
    const float* opw  = (const float*)d_in[18];
    const float* opb  = (const float*)d_in[19];
    const float* fcw  = (const float*)d_in[20];
    const float* fcb  = (const float*)d_in[21];
    float* ws  = (float*)d_ws;
    float* out = (float*)d_out;
    int* IB = (int*)(ws + O_AO);

    // zero: counts + cursors (5.5MB) and bn stats (64 f)
    hipMemsetAsync(IB, 0, (size_t)(I_CUR)*sizeof(int), stream);
    hipMemsetAsync(ws + O_BN, 0, 64*sizeof(float), stream);

    k_bn_stats<<<8192,256,0,stream>>>(x, ws+O_BN);
    k_bn_final<<<1,64,0,stream>>>(ws+O_BN, bng, bnb);
    k_xt<<<172032,256,0,stream>>>(x, hcw, ws+O_A);
    k_hist<<<10752,256,0,stream>>>(hi, IB+I_CNTD, IB+I_CNTB);
    k_fusew<<<4851,256,0,stream>>>(ipw, wq, wk, wv, fcw, opw, ws+O_W);
    k_fuseb<<<15,256,0,stream>>>(ipw, ipb, bq, bk, bv, fcw, opb, fcb, ws+O_BE);

    // hop 1: group incidences by edge, gather xt rows -> e (Binv folded)
    k_alloc<<<672,1024,0,stream>>>(IB+I_CNTB, IB+I_CUR, IB+I_CURS);
    k_fill <<<10752,256,0,stream>>>(hi+EINC, hi, IB+I_CUR, IB+I_CSR);
    k_gath <<<172032,256,0,stream>>>(ws+O_A, IB+I_CSR, IB+I_CUR, IB+I_CNTB, ws+O_B);
    // hop 2: group incidences by node, gather e rows -> h (Dinv folded); h overwrites xt
    k_alloc<<<672,1024,0,stream>>>(IB+I_CNTD, IB+I_CUR, IB+I_CURS+1);
    k_fill <<<10752,256,0,stream>>>(hi, hi+EINC, IB+I_CUR, IB+I_CSR);
    k_gath <<<172032,256,0,stream>>>(ws+O_B, IB+I_CSR, IB+I_CUR, IB+I_CNTD, ws+O_A);

    k_seq<<<2048,256,0,stream>>>(ws+O_A, hcb, cw, cb, ws+O_SEQ);
    // h and e now dead: O_A becomes res, O_B becomes frag/qkv pool
    k_res<<<2048,256,0,stream>>>(x, ws+O_BN, pw, pb, ws+O_BE+1008, ws+O_A);
    k_frag<<<1024,256,0,stream>>>(ws+O_SEQ,            (short*)(ws+O_SEQF));
    k_frag<<<  63,256,0,stream>>>(ws+O_W,              (short*)(ws+O_W1F));
    k_frag<<< 168,256,0,stream>>>(ws+O_W+3*112896,     (short*)(ws+O_W2F));
    {   dim3 g1(512,16);
        k_gemm<<<g1,256,0,stream>>>((const bf16x8*)(ws+O_SEQF),(const bf16x8*)(ws+O_W1F),
                                    nullptr, ws+O_BE, ws+O_QKV, 63, 1008, 0); }
    k_attn2<<<2048,256,0,stream>>>(ws+O_QKV, (short*)(ws+O_AOF));
    {   dim3 g2(512,42);
        k_gemm<<<g2,256,0,stream>>>((const bf16x8*)(ws+O_AOF),(const bf16x8*)(ws+O_W2F),
                                    ws+O_A, nullptr, out, 168, 2688, 1); }
}

// Round 4
// 2057.833 us; speedup vs baseline: 2.5292x; 1.2650x over previous
//
#include <hip/hip_runtime.h>

#define N_    2048
#define CIN   16
#define T_    8
#define VM_   42
#define COUT  64
#define NODES (N_*T_*VM_)        // 688128
#define EINC  (4*NODES)          // 2752512
#define EMB   336
#define PERN  (T_*VM_*COUT)      // 21504
#define XPERN (CIN*T_*VM_)       // 5376

typedef __attribute__((ext_vector_type(8))) short bf16x8;
typedef __attribute__((ext_vector_type(4))) float f32x4;
typedef unsigned short ushort_t;

// ---- ws layout (floats) ----
static const size_t O_A   = 0;                       // xt(bf16) -> h(bf16) -> res(bf16)
static const size_t SZ_AB = (size_t)NODES*64;
static const size_t O_B   = SZ_AB;                   // e(bf16) -> frag/qkv pool
static const size_t O_SEQ = 2*SZ_AB;                 // (free)
static const size_t SZ_SEQ= (size_t)N_*8*EMB;
static const size_t O_AO  = O_SEQ+SZ_SEQ;            // CSR int pool
static const size_t O_D   = O_AO+SZ_SEQ;
static const size_t O_Bd  = O_D+NODES;
static const size_t O_BN  = O_Bd+NODES;              // bn stats/scale (64)
static const size_t O_W   = O_BN+64;                 // Wqkv_eff + Wfc_eff (f32)
static const size_t O_BE  = O_W + 3*EMB*EMB + (size_t)8*EMB*EMB;  // fused biases
// sub-pool inside O_B (valid after e is dead):
static const size_t O_SEQF = O_B;                // 1024*5632 sh
static const size_t O_W1F  = O_B + 2900000;      // 63*5632 sh
static const size_t O_W2F  = O_B + 3100000;      // 168*5632 sh
static const size_t O_AOF  = O_B + 3600000;      // 1024*5632 sh
static const size_t O_QKV  = O_B + 6600000;      // 16384*1008 f32
// ---- int pool (offsets in ints, relative to (int*)(ws+O_AO)) ----
#define I_CNTD 0
#define I_CNTB 688128
#define I_CURS 1376256
#define I_CUR  1376320
#define I_CSR  2064448

__device__ inline short bf16r(float f){
    unsigned u = __builtin_bit_cast(unsigned, f);
    u += 0x7FFFu + ((u>>16)&1u);
    return (short)(u>>16);
}
__device__ inline float b2f(ushort_t u){
    return __builtin_bit_cast(float, ((unsigned)u)<<16);
}

// 512 blocks: block b -> channel ci=b&15, n-group b>>4 (32 groups x 64 n)
// wave handles 16 n's; 2048 atomics total over 32 addresses.
__global__ __launch_bounds__(256) void k_bn_stats(const float* __restrict__ x, float* __restrict__ bn){
    int b=blockIdx.x, ci=b&15, grp=b>>4;
    int w=threadIdx.x>>6, lane=threadIdx.x&63;
    float s=0.f,q=0.f;
    for(int i=0;i<16;i++){
        int n = grp*64 + w*16 + i;
        const float4* r4 = (const float4*)(x + (size_t)n*XPERN + ci*336);
        for(int k=lane;k<84;k+=64){
            float4 v=r4[k];
            s += v.x+v.y+v.z+v.w;
            q += v.x*v.x+v.y*v.y+v.z*v.z+v.w*v.w;
        }
    }
    for(int off=32;off;off>>=1){ s+=__shfl_down(s,off); q+=__shfl_down(q,off); }
    if(lane==0){ atomicAdd(bn+ci,s); atomicAdd(bn+16+ci,q); }
}

__global__ void k_bn_final(float* bn, const float* __restrict__ g, const float* __restrict__ b){
    int c = threadIdx.x;
    if(c<16){
        const float inv = 1.f/(float)NODES;
        float mean = bn[c]*inv;
        float var  = bn[16+c]*inv - mean*mean;
        float rs   = rsqrtf(var+1e-5f);
        float sc   = g[c]*rs;
        bn[32+c] = sc;
        bn[48+c] = b[c]-mean*sc;
    }
}

__global__ __launch_bounds__(256) void k_xt(const float* __restrict__ x, const float* __restrict__ hcw, ushort_t* __restrict__ xt){
    size_t gid = (size_t)blockIdx.x*256 + threadIdx.x;
    int node = (int)(gid>>6); int co = (int)(gid&63);
    int n = node/336, tl = node%336;
    const float* xb = x + (size_t)n*XPERN + tl;
    const float* w  = hcw + co*16;
    float acc=0.f;
    #pragma unroll
    for(int ci=0;ci<16;ci++) acc += xb[ci*336]*w[ci];
    xt[gid]=(ushort_t)bf16r(acc);
}

__global__ __launch_bounds__(256) void k_hist(const int* __restrict__ hi, int* __restrict__ cntD, int* __restrict__ cntB){
    int i = blockIdx.x*256+threadIdx.x;
    if(i<EINC){ atomicAdd(cntD+hi[i],1); atomicAdd(cntB+hi[EINC+i],1); }
}

__global__ __launch_bounds__(1024) void k_alloc(const int* __restrict__ cnt, int* __restrict__ cur, int* __restrict__ cursor){
    __shared__ int wtot[16], woff[16], bbase;
    int gid = blockIdx.x*1024 + threadIdx.x;
    int w = threadIdx.x>>6, lane = threadIdx.x&63;
    int orig = cnt[gid];
    int incl = orig;
    #pragma unroll
    for(int off=1;off<64;off<<=1){
        int nv = __shfl_up(incl, off);
        if(lane>=off) incl += nv;
    }
    if(lane==63) wtot[w]=incl;
    __syncthreads();
    if(threadIdx.x==0){
        int run=0;
        #pragma unroll
        for(int i=0;i<16;i++){ woff[i]=run; run+=wtot[i]; }
        bbase = atomicAdd(cursor, run);
    }
    __syncthreads();
    cur[gid] = bbase + woff[w] + (incl - orig);
}

__global__ __launch_bounds__(256) void k_fill(const int* __restrict__ seg, const int* __restrict__ pay,
                                              int* __restrict__ cur, int* __restrict__ csr){
    int i = blockIdx.x*256+threadIdx.x;
    if(i<EINC){
        int p = atomicAdd(cur+seg[i], 1);
        csr[p] = pay[i];
    }
}

// dst[s*64+lane] = (1/cnt[s]) * sum_j src[csr[j]*64+lane]   (bf16 rows, f32 accumulate)
__global__ __launch_bounds__(256) void k_gath(const ushort_t* __restrict__ src, const int* __restrict__ csr,
                                              const int* __restrict__ cur, const int* __restrict__ cnt,
                                              ushort_t* __restrict__ dst){
    int s = blockIdx.x*4 + (threadIdx.x>>6);
    int lane = threadIdx.x & 63;
    int c = cnt[s];
    int end = cur[s];
    int start = end - c;
    float acc = 0.f;
    int nv = (c<64)? c : 64;
    int myidx = (lane<nv)? csr[start+lane] : 0;
    for(int j=0;j<nv;j++){
        int idx = __shfl(myidx, j);
        acc += b2f(src[(size_t)idx*64 + lane]);
    }
    for(int j=64;j<c;j++){
        int idx = csr[start+j];
        acc += b2f(src[(size_t)idx*64 + lane]);
    }
    float scale = (c>0)? 1.f/(float)c : 0.f;
    dst[(size_t)s*64 + lane] = (ushort_t)bf16r(acc*scale);
}

// temporal conv + direct bf16 fragment emission (rows n*8+o of GEMM A, K padded to 352)
__global__ __launch_bounds__(256) void k_seq(const ushort_t* __restrict__ h,
                                             const float* __restrict__ hcb, const float* __restrict__ cw,
                                             const float* __restrict__ cb, short* __restrict__ seqf){
    __shared__ float hb[64], cws[64], cbs[8];
    int n = blockIdx.x, tid=threadIdx.x;
    if(tid<64){ hb[tid]=hcb[tid]; cws[tid]=cw[tid]; }
    if(tid<8) cbs[tid]=cb[tid];
    __syncthreads();
    const ushort_t* hn = h + (size_t)n*PERN;
    int rbase = (n&1)*8;
    short* d0 = seqf + (size_t)(n>>1)*5632;
    for(int e=tid; e<336; e+=256){
        int k = e/42, u = e%42;
        float hv[8];
        #pragma unroll
        for(int t=0;t<8;t++){
            int idx = 2688*k + t*42 + u;
            hv[t] = b2f(hn[idx]) + hb[idx&63];
        }
        int lpart = ((e>>3)&3)<<4;
        size_t obase = (size_t)(e>>5)*512 + (e&7);
        #pragma unroll
        for(int o=0;o<8;o++){
            float acc=cbs[o];
            #pragma unroll
            for(int t=0;t<8;t++) acc += cws[o*8+t]*hv[t];
            d0[obase + (size_t)((rbase+o)|lpart)*8] = bf16r(acc);
        }
    }
    if(tid<128){   // zero the K-pad 336..351 for this block's 8 rows
        int o=tid>>4, kk=336+(tid&15);
        int l=(rbase+o)|(((kk>>3)&3)<<4);
        d0[(size_t)(kk>>5)*512 + (size_t)l*8 + (kk&7)] = 0;
    }
}

__global__ __launch_bounds__(256) void k_fusew(const float* __restrict__ ipw, const float* __restrict__ wq,
                                               const float* __restrict__ wk, const float* __restrict__ wv,
                                               const float* __restrict__ fcw, const float* __restrict__ opw,
                                               float* __restrict__ W){
    int gid = blockIdx.x*256+threadIdx.x;
    float acc=0.f;
    if(gid < 3*112896){
        int m = gid/112896, r = gid%112896, o = r/336, i = r%336;
        const float* A  = ipw + (size_t)(m*336+o)*336;
        const float* Bm = (m==0)?wq:((m==1)?wk:wv);
        for(int k=0;k<336;k++) acc += A[k]*Bm[k*336+i];
    } else {
        int g2 = gid-3*112896; int j=g2/336, i=g2%336;
        const float* A = fcw + (size_t)j*336;
        for(int k=0;k<336;k++) acc += A[k]*opw[k*336+i];
    }
    W[gid]=acc;
}

__global__ __launch_bounds__(256) void k_fuseb(const float* __restrict__ ipw, const float* __restrict__ ipb,
                                               const float* __restrict__ bq, const float* __restrict__ bk,
                                               const float* __restrict__ bv, const float* __restrict__ fcw,
                                               const float* __restrict__ opb, const float* __restrict__ fcb,
                                               float* __restrict__ BE){
    int gid = blockIdx.x*256+threadIdx.x;
    if(gid<1008){
        int m=gid/336;
        const float* A  = ipw + (size_t)gid*336;
        const float* bm = (m==0)?bq:((m==1)?bk:bv);
        float acc=ipb[gid];
        for(int k=0;k<336;k++) acc+=A[k]*bm[k];
        BE[gid]=acc;
    } else if(gid<3696){
        int j=gid-1008;
        const float* A = fcw+(size_t)j*336;
        float acc=fcb[j];
        for(int k=0;k<336;k++) acc+=A[k]*opb[k];
        BE[gid]=acc;
    }
}

__global__ __launch_bounds__(256) void k_res(const float* __restrict__ x, const float* __restrict__ bn,
                                             const float* __restrict__ pw, const float* __restrict__ pb,
                                             const float* __restrict__ bfc, ushort_t* __restrict__ res){
    __shared__ float xp[5376], pws[1024], pbs[64], scs[16], shs[16];
    int n=blockIdx.x, tid=threadIdx.x;
    if(tid<16){ scs[tid]=bn[32+tid]; shs[tid]=bn[48+tid]; }
    if(tid<64) pbs[tid]=pb[tid];
    for(int f=tid;f<1024;f+=256) pws[f]=pw[f];
    __syncthreads();
    const float* xn = x + (size_t)n*XPERN;
    for(int f=tid;f<5376;f+=256){ int ci=f/336; xp[f]=xn[f]*scs[ci]+shs[ci]; }
    __syncthreads();
    ushort_t* rn = res + (size_t)n*PERN;
    for(int j=tid;j<2688;j+=256){
        int co=j&63, w=j>>6;
        float base = bfc[j]+pbs[co];
        float a[8];
        #pragma unroll
        for(int s=0;s<8;s++) a[s]=base;
        #pragma unroll
        for(int ci=0;ci<16;ci++){
            float c=pws[co*16+ci];
            const float* xr = xp + ci*336 + w;
            #pragma unroll
            for(int s=0;s<8;s++) a[s]+=c*xr[s*42];
        }
        #pragma unroll
        for(int s=0;s<8;s++) rn[s*2688+j]=(ushort_t)bf16r(a[s]);
    }
}

// f32 [rt*16+row][336] row-major -> bf16 fragments (weights only now)
__global__ __launch_bounds__(256) void k_frag(const float* __restrict__ src, short* __restrict__ dst){
    int rt=blockIdx.x, tid=threadIdx.x;
    const float* s0 = src + (size_t)rt*16*336;
    short* d0 = dst + (size_t)rt*5632;
    for(int idx=tid; idx<5632; idx+=256){
        int kb=idx>>9, rem=idx&511, l=rem>>3, j=rem&7;
        int row=l&15, k=kb*32+((l>>4)<<3)+j;
        float v = (k<336)? s0[row*336+k] : 0.f;
        d0[idx]=bf16r(v);
    }
}

__global__ __launch_bounds__(256) void k_gemm(const bf16x8* __restrict__ Af, const bf16x8* __restrict__ Wf,
                                              const ushort_t* __restrict__ addterm, const float* __restrict__ bias,
                                              float* __restrict__ C, int CT, int CW, int relu){
    int wv = threadIdx.x>>6, l = threadIdx.x&63;
    int ct = blockIdx.y*4 + wv;
    if(ct>=CT) return;
    int rt0 = blockIdx.x*2;
    const bf16x8* Ap = Af + (size_t)rt0*704 + l;
    const bf16x8* Bp = Wf + (size_t)ct *704 + l;
    f32x4 acc0={0.f,0.f,0.f,0.f}, acc1={0.f,0.f,0.f,0.f};
    #pragma unroll
    for(int kb=0;kb<11;kb++){
        bf16x8 b  = Bp[kb*64];
        bf16x8 a0 = Ap[kb*64];
        bf16x8 a1 = Ap[704 + kb*64];
        acc0 = __builtin_amdgcn_mfma_f32_16x16x32_bf16(a0,b,acc0,0,0,0);
        acc1 = __builtin_amdgcn_mfma_f32_16x16x32_bf16(a1,b,acc1,0,0,0);
    }
    int col = ct*16 + (l&15);
    int r   = rt0*16 + (l>>4)*4;
    float bb = bias ? bias[col] : 0.f;
    #pragma unroll
    for(int rr=0;rr<4;rr++){
        size_t o0 = (size_t)(r+rr)*CW + col;
        size_t o1 = (size_t)(r+16+rr)*CW + col;
        float v0 = acc0[rr] + bb;
        float v1 = acc1[rr] + bb;
        if(addterm){ v0 += b2f(addterm[o0]); v1 += b2f(addterm[o1]); }
        if(relu){ v0 = fmaxf(v0,0.f); v1 = fmaxf(v1,0.f); }
        C[o0]=v0; C[o1]=v1;
    }
}

__global__ __launch_bounds__(256) void k_attn2(const float* __restrict__ qkv, short* __restrict__ aof){
    __shared__ float ss[8*1008];
    __shared__ float sc[256];
    __shared__ float aos[8*336];
    int n=blockIdx.x, tid=threadIdx.x;
    const float* src = qkv + (size_t)n*8064;
    for(int f=tid; f<8064; f+=256) ss[f]=src[f];
    __syncthreads();
    {
        int h=tid>>6, s=(tid>>3)&7, t=tid&7;
        const float* qp=ss + s*1008 + h*84;
        const float* kp=ss + t*1008 + 336 + h*84;
        float d=0.f;
        for(int d0=0;d0<84;d0++) d+=qp[d0]*kp[d0];
        sc[tid]=d*0.10910894511799619f;
    }
    __syncthreads();
    if(tid<32){
        float* row = sc + (tid>>3)*64 + (tid&7)*8;
        float m=row[0];
        #pragma unroll
        for(int t=1;t<8;t++) m=fmaxf(m,row[t]);
        float sum=0.f;
        #pragma unroll
        for(int t=0;t<8;t++){ float e=__expf(row[t]-m); row[t]=e; sum+=e; }
        float r=1.f/sum;
        #pragma unroll
        for(int t=0;t<8;t++) row[t]*=r;
    }
    __syncthreads();
    for(int o=tid;o<336;o+=256){
        int h=o/84;
        float acc[8];
        #pragma unroll
        for(int s=0;s<8;s++) acc[s]=0.f;
        #pragma unroll
        for(int t=0;t<8;t++){
            float v=ss[t*1008+672+o];
            #pragma unroll
            for(int s=0;s<8;s++) acc[s]+=sc[h*64+s*8+t]*v;
        }
        #pragma unroll
        for(int s=0;s<8;s++) aos[s*336+o]=acc[s];
    }
    __syncthreads();
    int rt=n>>1, half=n&1;
    for(int e=tid; e<2816; e+=256){
        int row=e&7, k=e>>3;
        float v = (k<336)? aos[row*336+k] : 0.f;
        int l = (half*8+row) | (((k>>3)&3)<<4);
        int j = k&7;
        aof[(size_t)rt*5632 + (size_t)(k>>5)*512 + l*8 + j] = bf16r(v);
    }
}

extern "C" void kernel_launch(void* const* d_in, const int* in_sizes, int n_in,
                              void* d_out, int out_size, void* d_ws, size_t ws_size,
                              hipStream_t stream) {
    const float* x    = (const float*)d_in[0];
    const int*   hi   = (const int*  )d_in[1];
    const float* hcw  = (const float*)d_in[2];
    const float* hcb  = (const float*)d_in[3];
    const float* cw   = (const float*)d_in[4];
    const float* cb   = (const float*)d_in[5];
    const float* bng  = (const float*)d_in[6];
    const float* bnb  = (const float*)d_in[7];
    const float* pw   = (const float*)d_in[8];
    const float* pb   = (const float*)d_in[9];
    const float* wq   = (const float*)d_in[10];
    const float* bq   = (const float*)d_in[11];
    const float* wk   = (const float*)d_in[12];
    const float* bk   = (const float*)d_in[13];
    const float* wv   = (const float*)d_in[14];
    const float* bv   = (const float*)d_in[15];
    const float* ipw  = (const float*)d_in[16];
    const float* ipb  = (const float*)d_in[17];
    const float* opw  = (const float*)d_in[18];
    const float* opb  = (const float*)d_in[19];
    const float* fcw  = (const float*)d_in[20];
    const float* fcb  = (const float*)d_in[21];
    float* ws  = (float*)d_ws;
    float* out = (float*)d_out;
    int* IB = (int*)(ws + O_AO);

    hipMemsetAsync(IB, 0, (size_t)(I_CUR)*sizeof(int), stream);
    hipMemsetAsync(ws + O_BN, 0, 64*sizeof(float), stream);

    k_bn_stats<<<512,256,0,stream>>>(x, ws+O_BN);
    k_bn_final<<<1,64,0,stream>>>(ws+O_BN, bng, bnb);
    k_xt<<<172032,256,0,stream>>>(x, hcw, (ushort_t*)(ws+O_A));
    k_hist<<<10752,256,0,stream>>>(hi, IB+I_CNTD, IB+I_CNTB);
    k_fusew<<<4851,256,0,stream>>>(ipw, wq, wk, wv, fcw, opw, ws+O_W);
    k_fuseb<<<15,256,0,stream>>>(ipw, ipb, bq, bk, bv, fcw, opb, fcb, ws+O_BE);

    // hop 1: group by edge, gather xt rows -> e
    k_alloc<<<672,1024,0,stream>>>(IB+I_CNTB, IB+I_CUR, IB+I_CURS);
    k_fill <<<10752,256,0,stream>>>(hi+EINC, hi, IB+I_CUR, IB+I_CSR);
    k_gath <<<172032,256,0,stream>>>((const ushort_t*)(ws+O_A), IB+I_CSR, IB+I_CUR, IB+I_CNTB, (ushort_t*)(ws+O_B));
    // hop 2: group by node, gather e rows -> h (overwrites xt)
    k_alloc<<<672,1024,0,stream>>>(IB+I_CNTD, IB+I_CUR, IB+I_CURS+1);
    k_fill <<<10752,256,0,stream>>>(hi, hi+EINC, IB+I_CUR, IB+I_CSR);
    k_gath <<<172032,256,0,stream>>>((const ushort_t*)(ws+O_B), IB+I_CSR, IB+I_CUR, IB+I_CNTD, (ushort_t*)(ws+O_A));

    // e dead -> O_B becomes frag/qkv pool; seq emits fragments directly
    k_seq<<<2048,256,0,stream>>>((const ushort_t*)(ws+O_A), hcb, cw, cb, (short*)(ws+O_SEQF));
    // h dead -> O_A becomes res (bf16)
    k_res<<<2048,256,0,stream>>>(x, ws+O_BN, pw, pb, ws+O_BE+1008, (ushort_t*)(ws+O_A));
    k_frag<<<  63,256,0,stream>>>(ws+O_W,            (short*)(ws+O_W1F));
    k_frag<<< 168,256,0,stream>>>(ws+O_W+3*112896,   (short*)(ws+O_W2F));
    {   dim3 g1(512,16);
        k_gemm<<<g1,256,0,stream>>>((const bf16x8*)(ws+O_SEQF),(const bf16x8*)(ws+O_W1F),
                                    nullptr, ws+O_BE, ws+O_QKV, 63, 1008, 0); }
    k_attn2<<<2048,256,0,stream>>>(ws+O_QKV, (short*)(ws+O_AOF));
    {   dim3 g2(512,42);
        k_gemm<<<g2,256,0,stream>>>((const bf16x8*)(ws+O_AOF),(const bf16x8*)(ws+O_W2F),
                                    (const ushort_t*)(ws+O_A), nullptr, out, 168, 2688, 1); }
}

// Round 5
// 1656.439 us; speedup vs baseline: 3.1420x; 1.2423x over previous
//
#include <hip/hip_runtime.h>

#define N_    2048
#define CIN   16
#define T_    8
#define VM_   42
#define COUT  64
#define NODES (N_*T_*VM_)        // 688128
#define EINC  (4*NODES)          // 2752512
#define EMB   336
#define PERN  (T_*VM_*COUT)      // 21504
#define XPERN (CIN*T_*VM_)       // 5376

typedef __attribute__((ext_vector_type(8))) short bf16x8;
typedef __attribute__((ext_vector_type(4))) float f32x4;
typedef unsigned short ushort_t;

// ---- ws layout (floats) ----
static const size_t O_A   = 0;                       // xt(bf16) -> h(bf16) -> res(bf16)
static const size_t SZ_AB = (size_t)NODES*64;
static const size_t O_B   = SZ_AB;                   // e(bf16) -> frag/qkv pool
static const size_t O_SEQ = 2*SZ_AB;                 // int pool #2 (curD + csr2)
static const size_t SZ_SEQ= (size_t)N_*8*EMB;
static const size_t O_AO  = O_SEQ+SZ_SEQ;            // int pool #1
static const size_t O_D   = O_AO+SZ_SEQ;
static const size_t O_Bd  = O_D+NODES;
static const size_t O_BN  = O_Bd+NODES;              // bn stats/scale (64)
static const size_t O_W   = O_BN+64;                 // (unused now)
static const size_t O_BE  = O_W + 3*EMB*EMB + (size_t)8*EMB*EMB;  // fused biases (3696)
// sub-pool inside O_B (valid after e is dead):
static const size_t O_SEQF = O_B;                // 1024*5632 sh
static const size_t O_W1F  = O_B + 2900000;      // 63*5632 sh
static const size_t O_W2F  = O_B + 3100000;      // 168*5632 sh
static const size_t O_AOF  = O_B + 3600000;      // 1024*5632 sh
static const size_t O_QKV  = O_B + 6600000;      // 16384*1008 f32
// ---- int pool #1 (offsets in ints, rel to IB=(int*)(ws+O_AO)) ----
#define I_CNTD 0
#define I_CNTB 688128
#define I_CURS 1376256
#define I_CURB 1376320
#define I_CSR1 2064448           // end 4,816,960 < 5,505,024
// ---- int pool #2 (rel to IB2=(int*)(ws+O_SEQ)) ----
#define I2_CURD 0
#define I2_CSR2 688128           // end 3,440,640 < 5,505,024

__device__ inline short bf16r(float f){
    unsigned u = __builtin_bit_cast(unsigned, f);
    u += 0x7FFFu + ((u>>16)&1u);
    return (short)(u>>16);
}
__device__ inline float b2f(ushort_t u){
    return __builtin_bit_cast(float, ((unsigned)u)<<16);
}

__global__ __launch_bounds__(256) void k_bn_stats(const float* __restrict__ x, float* __restrict__ bn){
    int b=blockIdx.x, ci=b&15, grp=b>>4;
    int w=threadIdx.x>>6, lane=threadIdx.x&63;
    float s=0.f,q=0.f;
    for(int i=0;i<16;i++){
        int n = grp*64 + w*16 + i;
        const float4* r4 = (const float4*)(x + (size_t)n*XPERN + ci*336);
        for(int k=lane;k<84;k+=64){
            float4 v=r4[k];
            s += v.x+v.y+v.z+v.w;
            q += v.x*v.x+v.y*v.y+v.z*v.z+v.w*v.w;
        }
    }
    for(int off=32;off;off>>=1){ s+=__shfl_down(s,off); q+=__shfl_down(q,off); }
    if(lane==0){ atomicAdd(bn+ci,s); atomicAdd(bn+16+ci,q); }
}

__global__ void k_bn_final(float* bn, const float* __restrict__ g, const float* __restrict__ b){
    int c = threadIdx.x;
    if(c<16){
        const float inv = 1.f/(float)NODES;
        float mean = bn[c]*inv;
        float var  = bn[16+c]*inv - mean*mean;
        float rs   = rsqrtf(var+1e-5f);
        float sc   = g[c]*rs;
        bn[32+c] = sc;
        bn[48+c] = b[c]-mean*sc;
    }
}

// block per n: stage x row (5376 f) in LDS, write xt[node][co] bf16 coalesced
__global__ __launch_bounds__(256) void k_xt(const float* __restrict__ x, const float* __restrict__ hcw, ushort_t* __restrict__ xt){
    __shared__ float xs[5376];
    int n=blockIdx.x, tid=threadIdx.x;
    const float4* xr4=(const float4*)(x+(size_t)n*XPERN);
    float4* xs4=(float4*)xs;
    for(int f=tid; f<1344; f+=256) xs4[f]=xr4[f];
    int co=tid&63, q=tid>>6;
    float w[16];
    #pragma unroll
    for(int ci=0;ci<16;ci++) w[ci]=hcw[co*16+ci];
    __syncthreads();
    ushort_t* xn = xt + (size_t)n*336*64;
    for(int g=0; g<21; g++){
        int tl0 = q*84 + g*4;
        float4 acc={0.f,0.f,0.f,0.f};
        #pragma unroll
        for(int ci=0;ci<16;ci++){
            float4 xv = *(const float4*)(xs + ci*336 + tl0);
            acc.x+=xv.x*w[ci]; acc.y+=xv.y*w[ci]; acc.z+=xv.z*w[ci]; acc.w+=xv.w*w[ci];
        }
        xn[(size_t)(tl0+0)*64+co]=(ushort_t)bf16r(acc.x);
        xn[(size_t)(tl0+1)*64+co]=(ushort_t)bf16r(acc.y);
        xn[(size_t)(tl0+2)*64+co]=(ushort_t)bf16r(acc.z);
        xn[(size_t)(tl0+3)*64+co]=(ushort_t)bf16r(acc.w);
    }
}

__global__ __launch_bounds__(256) void k_hist(const int* __restrict__ hi, int* __restrict__ cntD, int* __restrict__ cntB){
    int i = blockIdx.x*256+threadIdx.x;
    if(i<EINC){ atomicAdd(cntD+hi[i],1); atomicAdd(cntB+hi[EINC+i],1); }
}

__global__ __launch_bounds__(1024) void k_alloc(const int* __restrict__ cnt, int* __restrict__ cur, int* __restrict__ cursor){
    __shared__ int wtot[16], woff[16], bbase;
    int gid = blockIdx.x*1024 + threadIdx.x;
    int w = threadIdx.x>>6, lane = threadIdx.x&63;
    int orig = cnt[gid];
    int incl = orig;
    #pragma unroll
    for(int off=1;off<64;off<<=1){
        int nv = __shfl_up(incl, off);
        if(lane>=off) incl += nv;
    }
    if(lane==63) wtot[w]=incl;
    __syncthreads();
    if(threadIdx.x==0){
        int run=0;
        #pragma unroll
        for(int i=0;i<16;i++){ woff[i]=run; run+=wtot[i]; }
        bbase = atomicAdd(cursor, run);
    }
    __syncthreads();
    cur[gid] = bbase + woff[w] + (incl - orig);
}

// both hops' CSR fills in one pass over hi
__global__ __launch_bounds__(256) void k_fill2(const int* __restrict__ hi, int* __restrict__ curB, int* __restrict__ curD,
                                               int* __restrict__ csr1, int* __restrict__ csr2){
    int i=blockIdx.x*256+threadIdx.x;
    if(i<EINC){
        int ni=hi[i], ei=hi[EINC+i];
        int p1=atomicAdd(curB+ei,1); csr1[p1]=ni;
        int p2=atomicAdd(curD+ni,1); csr2[p2]=ei;
    }
}

// 2 segments per wave; 32-lane groups, ushort2 per lane (128B per row read)
__global__ __launch_bounds__(256) void k_gath(const ushort_t* __restrict__ src, const int* __restrict__ csr,
                                              const int* __restrict__ cur, const int* __restrict__ cnt,
                                              ushort_t* __restrict__ dst){
    int s = blockIdx.x*8 + (threadIdx.x>>5);
    int l = threadIdx.x & 31;
    int c = cnt[s];
    int end = cur[s];
    int start = end - c;
    float ax=0.f, ay=0.f;
    int nv = (c<32)? c : 32;
    int myidx = (l<nv)? csr[start+l] : 0;
    for(int j=0;j<nv;j++){
        int idx = __shfl(myidx, j, 32);
        ushort2 v = *(const ushort2*)(src + (size_t)idx*64 + l*2);
        ax += b2f(v.x); ay += b2f(v.y);
    }
    for(int j=32;j<c;j++){
        int idx = csr[start+j];
        ushort2 v = *(const ushort2*)(src + (size_t)idx*64 + l*2);
        ax += b2f(v.x); ay += b2f(v.y);
    }
    float scale = (c>0)? 1.f/(float)c : 0.f;
    ushort2 o; o.x=(ushort_t)bf16r(ax*scale); o.y=(ushort_t)bf16r(ay*scale);
    *(ushort2*)(dst + (size_t)s*64 + l*2) = o;
}

// temporal conv + direct bf16 fragment emission (rows n*8+o of GEMM A, K padded to 352)
__global__ __launch_bounds__(256) void k_seq(const ushort_t* __restrict__ h,
                                             const float* __restrict__ hcb, const float* __restrict__ cw,
                                             const float* __restrict__ cb, short* __restrict__ seqf){
    __shared__ float hb[64], cws[64], cbs[8];
    int n = blockIdx.x, tid=threadIdx.x;
    if(tid<64){ hb[tid]=hcb[tid]; cws[tid]=cw[tid]; }
    if(tid<8) cbs[tid]=cb[tid];
    __syncthreads();
    const ushort_t* hn = h + (size_t)n*PERN;
    int rbase = (n&1)*8;
    short* d0 = seqf + (size_t)(n>>1)*5632;
    for(int e=tid; e<336; e+=256){
        int k = e/42, u = e%42;
        float hv[8];
        #pragma unroll
        for(int t=0;t<8;t++){
            int idx = 2688*k + t*42 + u;
            hv[t] = b2f(hn[idx]) + hb[idx&63];
        }
        int lpart = ((e>>3)&3)<<4;
        size_t obase = (size_t)(e>>5)*512 + (e&7);
        #pragma unroll
        for(int o=0;o<8;o++){
            float acc=cbs[o];
            #pragma unroll
            for(int t=0;t<8;t++) acc += cws[o*8+t]*hv[t];
            d0[obase + (size_t)((rbase+o)|lpart)*8] = bf16r(acc);
        }
    }
    if(tid<128){   // zero the K-pad 336..351 for this block's 8 rows
        int o=tid>>4, kk=336+(tid&15);
        int l=(rbase+o)|(((kk>>3)&3)<<4);
        d0[(size_t)(kk>>5)*512 + (size_t)l*8 + (kk&7)] = 0;
    }
}

// fused weight-GEMM (16-row tile) + bias fold + direct bf16 fragment emission
// rows 0..1007: Wqkv_eff = ipw @ (wq|wk|wv); rows 1008..3695: Wfc_eff = fcw @ opw
__global__ __launch_bounds__(256) void k_fusew2(const float* __restrict__ ipw, const float* __restrict__ ipb,
        const float* __restrict__ wq, const float* __restrict__ wk, const float* __restrict__ wv,
        const float* __restrict__ bq, const float* __restrict__ bk, const float* __restrict__ bv,
        const float* __restrict__ fcw, const float* __restrict__ opw,
        const float* __restrict__ opb, const float* __restrict__ fcb,
        short* __restrict__ W1F, short* __restrict__ W2F, float* __restrict__ BE){
    __shared__ float As[5376], Ws[5376], bms[336];
    int rt=blockIdx.x, r0=rt*16, tid=threadIdx.x;
    int m=(r0<1008)?(r0/336):3;
    const float* Asrc = (m<3)? (ipw+(size_t)r0*336) : (fcw+(size_t)(r0-1008)*336);
    const float* Bmat = (m==0)?wq:((m==1)?wk:((m==2)?wv:opw));
    const float* bvec = (m==0)?bq:((m==1)?bk:((m==2)?bv:opb));
    for(int f=tid;f<5376;f+=256) As[f]=Asrc[f];
    for(int f=tid;f<336;f+=256) bms[f]=bvec[f];
    __syncthreads();
    if(tid<168){
        int i0=tid, i1=tid+168;
        float a0[16], a1[16];
        #pragma unroll
        for(int r=0;r<16;r++){a0[r]=0.f;a1[r]=0.f;}
        for(int k=0;k<336;k++){
            float b0=Bmat[(size_t)k*336+i0];
            float b1=Bmat[(size_t)k*336+i1];
            #pragma unroll
            for(int r=0;r<16;r++){ float av=As[r*336+k]; a0[r]+=av*b0; a1[r]+=av*b1; }
        }
        #pragma unroll
        for(int r=0;r<16;r++){ Ws[r*336+i0]=a0[r]; Ws[r*336+i1]=a1[r]; }
    }
    if(tid>=192 && tid<208){
        int rr=tid-192;
        float acc=(m<3)? ipb[r0+rr] : fcb[r0+rr-1008];
        for(int k=0;k<336;k++) acc+=As[rr*336+k]*bms[k];
        BE[r0+rr]=acc;
    }
    __syncthreads();
    short* dst=(m<3)? (W1F+(size_t)rt*5632) : (W2F+(size_t)(rt-63)*5632);
    for(int f=tid; f<5632; f+=256){
        int kb=f>>9, rem=f&511, l=rem>>3, j=rem&7;
        int row=l&15, k=kb*32+((l>>4)<<3)+j;
        dst[f] = (k<336)? bf16r(Ws[row*336+k]) : (short)0;
    }
}

__global__ __launch_bounds__(256) void k_res(const float* __restrict__ x, const float* __restrict__ bn,
                                             const float* __restrict__ pw, const float* __restrict__ pb,
                                             const float* __restrict__ bfc, ushort_t* __restrict__ res){
    __shared__ float xp[5376], pws[1024], pbs[64], scs[16], shs[16];
    int n=blockIdx.x, tid=threadIdx.x;
    if(tid<16){ scs[tid]=bn[32+tid]; shs[tid]=bn[48+tid]; }
    if(tid<64) pbs[tid]=pb[tid];
    for(int f=tid;f<1024;f+=256) pws[f]=pw[f];
    __syncthreads();
    const float* xn = x + (size_t)n*XPERN;
    for(int f=tid;f<5376;f+=256){ int ci=f/336; xp[f]=xn[f]*scs[ci]+shs[ci]; }
    __syncthreads();
    ushort_t* rn = res + (size_t)n*PERN;
    for(int j=tid;j<2688;j+=256){
        int co=j&63, w=j>>6;
        float base = bfc[j]+pbs[co];
        float a[8];
        #pragma unroll
        for(int s=0;s<8;s++) a[s]=base;
        #pragma unroll
        for(int ci=0;ci<16;ci++){
            float c=pws[co*16+ci];
            const float* xr = xp + ci*336 + w;
            #pragma unroll
            for(int s=0;s<8;s++) a[s]+=c*xr[s*42];
        }
        #pragma unroll
        for(int s=0;s<8;s++) rn[s*2688+j]=(ushort_t)bf16r(a[s]);
    }
}

__global__ __launch_bounds__(256) void k_gemm(const bf16x8* __restrict__ Af, const bf16x8* __restrict__ Wf,
                                              const ushort_t* __restrict__ addterm, const float* __restrict__ bias,
                                              float* __restrict__ C, int CT, int CW, int relu){
    int wv = threadIdx.x>>6, l = threadIdx.x&63;
    int ct = blockIdx.y*4 + wv;
    if(ct>=CT) return;
    int rt0 = blockIdx.x*2;
    const bf16x8* Ap = Af + (size_t)rt0*704 + l;
    const bf16x8* Bp = Wf + (size_t)ct *704 + l;
    f32x4 acc0={0.f,0.f,0.f,0.f}, acc1={0.f,0.f,0.f,0.f};
    #pragma unroll
    for(int kb=0;kb<11;kb++){
        bf16x8 b  = Bp[kb*64];
        bf16x8 a0 = Ap[kb*64];
        bf16x8 a1 = Ap[704 + kb*64];
        acc0 = __builtin_amdgcn_mfma_f32_16x16x32_bf16(a0,b,acc0,0,0,0);
        acc1 = __builtin_amdgcn_mfma_f32_16x16x32_bf16(a1,b,acc1,0,0,0);
    }
    int col = ct*16 + (l&15);
    int r   = rt0*16 + (l>>4)*4;
    float bb = bias ? bias[col] : 0.f;
    #pragma unroll
    for(int rr=0;rr<4;rr++){
        size_t o0 = (size_t)(r+rr)*CW + col;
        size_t o1 = (size_t)(r+16+rr)*CW + col;
        float v0 = acc0[rr] + bb;
        float v1 = acc1[rr] + bb;
        if(addterm){ v0 += b2f(addterm[o0]); v1 += b2f(addterm[o1]); }
        if(relu){ v0 = fmaxf(v0,0.f); v1 = fmaxf(v1,0.f); }
        C[o0]=v0; C[o1]=v1;
    }
}

__global__ __launch_bounds__(256) void k_attn2(const float* __restrict__ qkv, short* __restrict__ aof){
    __shared__ float ss[8*1008];
    __shared__ float sc[256];
    __shared__ float aos[8*336];
    int n=blockIdx.x, tid=threadIdx.x;
    const float* src = qkv + (size_t)n*8064;
    for(int f=tid; f<8064; f+=256) ss[f]=src[f];
    __syncthreads();
    {
        int h=tid>>6, s=(tid>>3)&7, t=tid&7;
        const float* qp=ss + s*1008 + h*84;
        const float* kp=ss + t*1008 + 336 + h*84;
        float d=0.f;
        for(int d0=0;d0<84;d0++) d+=qp[d0]*kp[d0];
        sc[tid]=d*0.10910894511799619f;
    }
    __syncthreads();
    if(tid<32){
        float* row = sc + (tid>>3)*64 + (tid&7)*8;
        float m=row[0];
        #pragma unroll
        for(int t=1;t<8;t++) m=fmaxf(m,row[t]);
        float sum=0.f;
        #pragma unroll
        for(int t=0;t<8;t++){ float e=__expf(row[t]-m); row[t]=e; sum+=e; }
        float r=1.f/sum;
        #pragma unroll
        for(int t=0;t<8;t++) row[t]*=r;
    }
    __syncthreads();
    for(int o=tid;o<336;o+=256){
        int h=o/84;
        float acc[8];
        #pragma unroll
        for(int s=0;s<8;s++) acc[s]=0.f;
        #pragma unroll
        for(int t=0;t<8;t++){
            float v=ss[t*1008+672+o];
            #pragma unroll
            for(int s=0;s<8;s++) acc[s]+=sc[h*64+s*8+t]*v;
        }
        #pragma unroll
        for(int s=0;s<8;s++) aos[s*336+o]=acc[s];
    }
    __syncthreads();
    int rt=n>>1, half=n&1;
    for(int e=tid; e<2816; e+=256){
        int row=e&7, k=e>>3;
        float v = (k<336)? aos[row*336+k] : 0.f;
        int l = (half*8+row) | (((k>>3)&3)<<4);
        int j = k&7;
        aof[(size_t)rt*5632 + (size_t)(k>>5)*512 + l*8 + j] = bf16r(v);
    }
}

extern "C" void kernel_launch(void* const* d_in, const int* in_sizes, int n_in,
                              void* d_out, int out_size, void* d_ws, size_t ws_size,
                              hipStream_t stream) {
    const float* x    = (const float*)d_in[0];
    const int*   hi   = (const int*  )d_in[1];
    const float* hcw  = (const float*)d_in[2];
    const float* hcb  = (const float*)d_in[3];
    const float* cw   = (const float*)d_in[4];
    const float* cb   = (const float*)d_in[5];
    const float* bng  = (const float*)d_in[6];
    const float* bnb  = (const float*)d_in[7];
    const float* pw   = (const float*)d_in[8];
    const float* pb   = (const float*)d_in[9];
    const float* wq   = (const float*)d_in[10];
    const float* bq   = (const float*)d_in[11];
    const float* wk   = (const float*)d_in[12];
    const float* bk   = (const float*)d_in[13];
    const float* wv   = (const float*)d_in[14];
    const float* bv   = (const float*)d_in[15];
    const float* ipw  = (const float*)d_in[16];
    const float* ipb  = (const float*)d_in[17];
    const float* opw  = (const float*)d_in[18];
    const float* opb  = (const float*)d_in[19];
    const float* fcw  = (const float*)d_in[20];
    const float* fcb  = (const float*)d_in[21];
    float* ws  = (float*)d_ws;
    float* out = (float*)d_out;
    int* IB  = (int*)(ws + O_AO);
    int* IB2 = (int*)(ws + O_SEQ);

    hipMemsetAsync(IB, 0, (size_t)(I_CURB)*sizeof(int), stream);   // counts + cursors
    hipMemsetAsync(ws + O_BN, 0, 64*sizeof(float), stream);

    k_bn_stats<<<512,256,0,stream>>>(x, ws+O_BN);
    k_bn_final<<<1,64,0,stream>>>(ws+O_BN, bng, bnb);
    k_xt<<<2048,256,0,stream>>>(x, hcw, (ushort_t*)(ws+O_A));
    k_hist<<<10752,256,0,stream>>>(hi, IB+I_CNTD, IB+I_CNTB);
    k_fusew2<<<231,256,0,stream>>>(ipw, ipb, wq, wk, wv, bq, bk, bv,
                                   fcw, opw, opb, fcb,
                                   (short*)(ws+O_W1F), (short*)(ws+O_W2F), ws+O_BE);

    k_alloc<<<672,1024,0,stream>>>(IB+I_CNTB, IB+I_CURB,  IB+I_CURS);     // edge segments
    k_alloc<<<672,1024,0,stream>>>(IB+I_CNTD, IB2+I2_CURD, IB+I_CURS+1);  // node segments
    k_fill2<<<10752,256,0,stream>>>(hi, IB+I_CURB, IB2+I2_CURD, IB+I_CSR1, IB2+I2_CSR2);
    // hop 1: edge-grouped gather of xt rows -> e
    k_gath<<<86016,256,0,stream>>>((const ushort_t*)(ws+O_A), IB+I_CSR1, IB+I_CURB, IB+I_CNTB, (ushort_t*)(ws+O_B));
    // hop 2: node-grouped gather of e rows -> h (overwrites xt)
    k_gath<<<86016,256,0,stream>>>((const ushort_t*)(ws+O_B), IB2+I2_CSR2, IB2+I2_CURD, IB+I_CNTD, (ushort_t*)(ws+O_A));

    // e dead -> O_B becomes frag/qkv pool; seq emits fragments directly
    k_seq<<<2048,256,0,stream>>>((const ushort_t*)(ws+O_A), hcb, cw, cb, (short*)(ws+O_SEQF));
    // h dead -> O_A becomes res (bf16)
    k_res<<<2048,256,0,stream>>>(x, ws+O_BN, pw, pb, ws+O_BE+1008, (ushort_t*)(ws+O_A));
    {   dim3 g1(512,16);
        k_gemm<<<g1,256,0,stream>>>((const bf16x8*)(ws+O_SEQF),(const bf16x8*)(ws+O_W1F),
                                    nullptr, ws+O_BE, ws+O_QKV, 63, 1008, 0); }
    k_attn2<<<2048,256,0,stream>>>(ws+O_QKV, (short*)(ws+O_AOF));
    {   dim3 g2(512,42);
        k_gemm<<<g2,256,0,stream>>>((const bf16x8*)(ws+O_AOF),(const bf16x8*)(ws+O_W2F),
                                    (const ushort_t*)(ws+O_A), nullptr, out, 168, 2688, 1); }
}

// Round 6
// 1048.767 us; speedup vs baseline: 4.9626x; 1.5794x over previous
//
#include <hip/hip_runtime.h>

#define N_    2048
#define CIN   16
#define T_    8
#define VM_   42
#define COUT  64
#define NODES (N_*T_*VM_)        // 688128
#define EINC  (4*NODES)          // 2752512
#define EMB   336
#define PERN  (T_*VM_*COUT)      // 21504
#define XPERN (CIN*T_*VM_)       // 5376
#define NBUK  672                // buckets = seg>>10 ; 672*1024 = 688128
#define BCAP  4608               // staging capacity per bucket (lambda=4096, 8 sigma)
#define LCAP  16                 // per-(block,bucket) LDS bin capacity (lambda=6.1)

typedef __attribute__((ext_vector_type(8))) short bf16x8;
typedef __attribute__((ext_vector_type(4))) float f32x4;
typedef unsigned short ushort_t;

// ---- ws layout (floats) ----
static const size_t O_A   = 0;                        // xt(bf16) -> h(bf16) -> res(bf16)
static const size_t SZ_AB = (size_t)NODES*64;         // 44,040,192
static const size_t O_B   = SZ_AB;                    // e(bf16) -> seqf/aof/qkv pool
static const size_t O_SEQ = 2*SZ_AB;                  // stagingE (3,096,576 u32) + gcurE/gcurD
static const size_t SZ_SEQ= (size_t)N_*8*EMB;         // 5,505,024
static const size_t O_AO  = O_SEQ+SZ_SEQ;             // stagingD
static const size_t O_SD  = O_AO+SZ_SEQ;              // startE,cntE,startD,cntD (4*NODES)
static const size_t O_BN  = O_SD + 4*(size_t)NODES;   // bn stats/scale (64)
static const size_t O_BE  = O_BN + 64;                // fused biases (3696)
static const size_t O_WF  = O_BE + 4096;              // W1F+W2F bf16 frags (231*5632 sh)
// sub-pool inside O_B (valid only after e is dead):
static const size_t O_SEQF = O_B;                 // 1024*5632 sh
static const size_t O_AOF  = O_B + 3600000;       // 1024*5632 sh
static const size_t O_QKV  = O_B + 6600000;       // 16384*1008 f32

__device__ inline short bf16r(float f){
    unsigned u = __builtin_bit_cast(unsigned, f);
    u += 0x7FFFu + ((u>>16)&1u);
    return (short)(u>>16);
}
__device__ inline float b2f(ushort_t u){
    return __builtin_bit_cast(float, ((unsigned)u)<<16);
}

__global__ __launch_bounds__(256) void k_bn_stats(const float* __restrict__ x, float* __restrict__ bn){
    int b=blockIdx.x, ci=b&15, grp=b>>4;
    int w=threadIdx.x>>6, lane=threadIdx.x&63;
    float s=0.f,q=0.f;
    for(int i=0;i<16;i++){
        int n = grp*64 + w*16 + i;
        const float4* r4 = (const float4*)(x + (size_t)n*XPERN + ci*336);
        for(int k=lane;k<84;k+=64){
            float4 v=r4[k];
            s += v.x+v.y+v.z+v.w;
            q += v.x*v.x+v.y*v.y+v.z*v.z+v.w*v.w;
        }
    }
    for(int off=32;off;off>>=1){ s+=__shfl_down(s,off); q+=__shfl_down(q,off); }
    if(lane==0){ atomicAdd(bn+ci,s); atomicAdd(bn+16+ci,q); }
}

__global__ void k_bn_final(float* bn, const float* __restrict__ g, const float* __restrict__ b){
    int c = threadIdx.x;
    if(c<16){
        const float inv = 1.f/(float)NODES;
        float mean = bn[c]*inv;
        float var  = bn[16+c]*inv - mean*mean;
        float rs   = rsqrtf(var+1e-5f);
        float sc   = g[c]*rs;
        bn[32+c] = sc;
        bn[48+c] = b[c]-mean*sc;
    }
}

__global__ __launch_bounds__(256) void k_xt(const float* __restrict__ x, const float* __restrict__ hcw, ushort_t* __restrict__ xt){
    __shared__ float xs[5376];
    int n=blockIdx.x, tid=threadIdx.x;
    const float4* xr4=(const float4*)(x+(size_t)n*XPERN);
    float4* xs4=(float4*)xs;
    for(int f=tid; f<1344; f+=256) xs4[f]=xr4[f];
    int co=tid&63, q=tid>>6;
    float w[16];
    #pragma unroll
    for(int ci=0;ci<16;ci++) w[ci]=hcw[co*16+ci];
    __syncthreads();
    ushort_t* xn = xt + (size_t)n*336*64;
    for(int g=0; g<21; g++){
        int tl0 = q*84 + g*4;
        float4 acc={0.f,0.f,0.f,0.f};
        #pragma unroll
        for(int ci=0;ci<16;ci++){
            float4 xv = *(const float4*)(xs + ci*336 + tl0);
            acc.x+=xv.x*w[ci]; acc.y+=xv.y*w[ci]; acc.z+=xv.z*w[ci]; acc.w+=xv.w*w[ci];
        }
        xn[(size_t)(tl0+0)*64+co]=(ushort_t)bf16r(acc.x);
        xn[(size_t)(tl0+1)*64+co]=(ushort_t)bf16r(acc.y);
        xn[(size_t)(tl0+2)*64+co]=(ushort_t)bf16r(acc.z);
        xn[(size_t)(tl0+3)*64+co]=(ushort_t)bf16r(acc.w);
    }
}

__global__ void k_initcur(int* __restrict__ gcurE, int* __restrict__ gcurD){
    int i=blockIdx.x*256+threadIdx.x;
    if(i<NBUK){ gcurE[i]=i*BCAP; gcurD[i]=i*BCAP; }
}

// bucket-bin incidences: entry = (seg&1023)<<20 | payload; bucket = seg>>10.
// LDS bins flushed as contiguous runs -> near-sequential writes per bucket region.
__global__ __launch_bounds__(256) void k_bin(const int* __restrict__ seg, const int* __restrict__ pay,
                                             int* __restrict__ gcur, unsigned* __restrict__ staging){
    __shared__ unsigned bins[NBUK*LCAP];
    __shared__ int lcnt[NBUK];
    int tid=threadIdx.x;
    for(int i=tid;i<NBUK;i+=256) lcnt[i]=0;
    __syncthreads();
    int base=blockIdx.x*4096;
    for(int k=0;k<16;k++){
        int i=base+k*256+tid;
        int sv=seg[i], pv=pay[i];
        int b=sv>>10;
        unsigned e=((unsigned)(sv&1023)<<20)|(unsigned)pv;
        int p=atomicAdd(&lcnt[b],1);
        if(p<LCAP) bins[b*LCAP+p]=e;
        else{
            int g=atomicAdd(&gcur[b],1);
            if(g<(b+1)*BCAP) staging[g]=e;
        }
    }
    __syncthreads();
    for(int b=tid;b<NBUK;b+=256){
        int c=lcnt[b]; if(c>LCAP)c=LCAP;
        if(c>0){
            int g=atomicAdd(&gcur[b],c);
            int lim=(b+1)*BCAP;
            for(int j=0;j<c;j++) if(g+j<lim) staging[g+j]=bins[b*LCAP+j];
        }
    }
}

// per-bucket in-LDS segment sort; writes payloads back in place + per-seg start/cnt
__global__ __launch_bounds__(256) void k_csrsort(unsigned* __restrict__ staging, const int* __restrict__ gcur,
                                                 int* __restrict__ startX, int* __restrict__ cntX){
    __shared__ unsigned ents[BCAP];
    __shared__ unsigned outp[BCAP];
    __shared__ int segc[1024];
    __shared__ int wsum[4];
    int b=blockIdx.x, tid=threadIdx.x, lane=tid&63, wv=tid>>6;
    int cnt_b = gcur[b] - b*BCAP;
    if(cnt_b>BCAP) cnt_b=BCAP;
    unsigned* sb = staging + (size_t)b*BCAP;
    for(int i=tid;i<cnt_b;i+=256) ents[i]=sb[i];
    for(int i=tid;i<1024;i+=256) segc[i]=0;
    __syncthreads();
    for(int i=tid;i<cnt_b;i+=256) atomicAdd(&segc[ents[i]>>20],1);
    __syncthreads();
    int c0=segc[tid*4],c1=segc[tid*4+1],c2=segc[tid*4+2],c3=segc[tid*4+3];
    int tsum=c0+c1+c2+c3;
    int incl=tsum;
    #pragma unroll
    for(int off=1;off<64;off<<=1){ int v=__shfl_up(incl,off); if(lane>=off) incl+=v; }
    if(lane==63) wsum[wv]=incl;
    __syncthreads();
    int w0=wsum[0],w1=wsum[1],w2=wsum[2];
    int wexcl = (wv>0?w0:0)+(wv>1?w1:0)+(wv>2?w2:0);
    int run = incl - tsum + wexcl;
    int gs = b*1024 + tid*4;
    startX[gs+0]=b*BCAP+run; cntX[gs+0]=c0; segc[tid*4+0]=run; run+=c0;
    startX[gs+1]=b*BCAP+run; cntX[gs+1]=c1; segc[tid*4+1]=run; run+=c1;
    startX[gs+2]=b*BCAP+run; cntX[gs+2]=c2; segc[tid*4+2]=run; run+=c2;
    startX[gs+3]=b*BCAP+run; cntX[gs+3]=c3; segc[tid*4+3]=run; run+=c3;
    __syncthreads();
    for(int i=tid;i<cnt_b;i+=256){
        unsigned e=ents[i]; int s=e>>20;
        int p=atomicAdd(&segc[s],1);
        outp[p]=e&0xFFFFFu;
    }
    __syncthreads();
    for(int i=tid;i<cnt_b;i+=256) sb[i]=outp[i];
}

// 2 segments per wave; 32-lane groups, ushort2 per lane
__global__ __launch_bounds__(256) void k_gath(const ushort_t* __restrict__ src, const int* __restrict__ csr,
                                              const int* __restrict__ startX, const int* __restrict__ cntX,
                                              ushort_t* __restrict__ dst){
    int s = blockIdx.x*8 + (threadIdx.x>>5);
    int l = threadIdx.x & 31;
    int c = cntX[s];
    int start = startX[s];
    float ax=0.f, ay=0.f;
    int nv = (c<32)? c : 32;
    int myidx = (l<nv)? csr[start+l] : 0;
    for(int j=0;j<nv;j++){
        int idx = __shfl(myidx, j, 32);
        ushort2 v = *(const ushort2*)(src + (size_t)idx*64 + l*2);
        ax += b2f(v.x); ay += b2f(v.y);
    }
    for(int j=32;j<c;j++){
        int idx = csr[start+j];
        ushort2 v = *(const ushort2*)(src + (size_t)idx*64 + l*2);
        ax += b2f(v.x); ay += b2f(v.y);
    }
    float scale = (c>0)? 1.f/(float)c : 0.f;
    ushort2 o; o.x=(ushort_t)bf16r(ax*scale); o.y=(ushort_t)bf16r(ay*scale);
    *(ushort2*)(dst + (size_t)s*64 + l*2) = o;
}

// temporal conv + direct bf16 fragment emission (rows n*8+o of GEMM A, K padded to 352)
__global__ __launch_bounds__(256) void k_seq(const ushort_t* __restrict__ h,
                                             const float* __restrict__ hcb, const float* __restrict__ cw,
                                             const float* __restrict__ cb, short* __restrict__ seqf){
    __shared__ float hb[64], cws[64], cbs[8];
    int n = blockIdx.x, tid=threadIdx.x;
    if(tid<64){ hb[tid]=hcb[tid]; cws[tid]=cw[tid]; }
    if(tid<8) cbs[tid]=cb[tid];
    __syncthreads();
    const ushort_t* hn = h + (size_t)n*PERN;
    int rbase = (n&1)*8;
    short* d0 = seqf + (size_t)(n>>1)*5632;
    for(int e=tid; e<336; e+=256){
        int k = e/42, u = e%42;
        float hv[8];
        #pragma unroll
        for(int t=0;t<8;t++){
            int idx = 2688*k + t*42 + u;
            hv[t] = b2f(hn[idx]) + hb[idx&63];
        }
        int lpart = ((e>>3)&3)<<4;
        size_t obase = (size_t)(e>>5)*512 + (e&7);
        #pragma unroll
        for(int o=0;o<8;o++){
            float acc=cbs[o];
            #pragma unroll
            for(int t=0;t<8;t++) acc += cws[o*8+t]*hv[t];
            d0[obase + (size_t)((rbase+o)|lpart)*8] = bf16r(acc);
        }
    }
    if(tid<128){
        int o=tid>>4, kk=336+(tid&15);
        int l=(rbase+o)|(((kk>>3)&3)<<4);
        d0[(size_t)(kk>>5)*512 + (size_t)l*8 + (kk&7)] = 0;
    }
}

// fused weight-GEMM (16-row tile) + bias fold + direct bf16 fragment emission
__global__ __launch_bounds__(256) void k_fusew2(const float* __restrict__ ipw, const float* __restrict__ ipb,
        const float* __restrict__ wq, const float* __restrict__ wk, const float* __restrict__ wv,
        const float* __restrict__ bq, const float* __restrict__ bk, const float* __restrict__ bv,
        const float* __restrict__ fcw, const float* __restrict__ opw,
        const float* __restrict__ opb, const float* __restrict__ fcb,
        short* __restrict__ W1F, short* __restrict__ W2F, float* __restrict__ BE){
    __shared__ float As[5376], Ws[5376], bms[336];
    int rt=blockIdx.x, r0=rt*16, tid=threadIdx.x;
    int m=(r0<1008)?(r0/336):3;
    const float* Asrc = (m<3)? (ipw+(size_t)r0*336) : (fcw+(size_t)(r0-1008)*336);
    const float* Bmat = (m==0)?wq:((m==1)?wk:((m==2)?wv:opw));
    const float* bvec = (m==0)?bq:((m==1)?bk:((m==2)?bv:opb));
    for(int f=tid;f<5376;f+=256) As[f]=Asrc[f];
    for(int f=tid;f<336;f+=256) bms[f]=bvec[f];
    __syncthreads();
    if(tid<168){
        int i0=tid, i1=tid+168;
        float a0[16], a1[16];
        #pragma unroll
        for(int r=0;r<16;r++){a0[r]=0.f;a1[r]=0.f;}
        for(int k=0;k<336;k++){
            float b0=Bmat[(size_t)k*336+i0];
            float b1=Bmat[(size_t)k*336+i1];
            #pragma unroll
            for(int r=0;r<16;r++){ float av=As[r*336+k]; a0[r]+=av*b0; a1[r]+=av*b1; }
        }
        #pragma unroll
        for(int r=0;r<16;r++){ Ws[r*336+i0]=a0[r]; Ws[r*336+i1]=a1[r]; }
    }
    if(tid>=192 && tid<208){
        int rr=tid-192;
        float acc=(m<3)? ipb[r0+rr] : fcb[r0+rr-1008];
        for(int k=0;k<336;k++) acc+=As[rr*336+k]*bms[k];
        BE[r0+rr]=acc;
    }
    __syncthreads();
    short* dst=(m<3)? (W1F+(size_t)rt*5632) : (W2F+(size_t)(rt-63)*5632);
    for(int f=tid; f<5632; f+=256){
        int kb=f>>9, rem=f&511, l=rem>>3, j=rem&7;
        int row=l&15, k=kb*32+((l>>4)<<3)+j;
        dst[f] = (k<336)? bf16r(Ws[row*336+k]) : (short)0;
    }
}

__global__ __launch_bounds__(256) void k_res(const float* __restrict__ x, const float* __restrict__ bn,
                                             const float* __restrict__ pw, const float* __restrict__ pb,
                                             const float* __restrict__ bfc, ushort_t* __restrict__ res){
    __shared__ float xp[5376], pws[1024], pbs[64], scs[16], shs[16];
    int n=blockIdx.x, tid=threadIdx.x;
    if(tid<16){ scs[tid]=bn[32+tid]; shs[tid]=bn[48+tid]; }
    if(tid<64) pbs[tid]=pb[tid];
    for(int f=tid;f<1024;f+=256) pws[f]=pw[f];
    __syncthreads();
    const float* xn = x + (size_t)n*XPERN;
    for(int f=tid;f<5376;f+=256){ int ci=f/336; xp[f]=xn[f]*scs[ci]+shs[ci]; }
    __syncthreads();
    ushort_t* rn = res + (size_t)n*PERN;
    for(int j=tid;j<2688;j+=256){
        int co=j&63, w=j>>6;
        float base = bfc[j]+pbs[co];
        float a[8];
        #pragma unroll
        for(int s=0;s<8;s++) a[s]=base;
        #pragma unroll
        for(int ci=0;ci<16;ci++){
            float c=pws[co*16+ci];
            const float* xr = xp + ci*336 + w;
            #pragma unroll
            for(int s=0;s<8;s++) a[s]+=c*xr[s*42];
        }
        #pragma unroll
        for(int s=0;s<8;s++) rn[s*2688+j]=(ushort_t)bf16r(a[s]);
    }
}

__global__ __launch_bounds__(256) void k_gemm(const bf16x8* __restrict__ Af, const bf16x8* __restrict__ Wf,
                                              const ushort_t* __restrict__ addterm, const float* __restrict__ bias,
                                              float* __restrict__ C, int CT, int CW, int relu){
    int wv = threadIdx.x>>6, l = threadIdx.x&63;
    int ct = blockIdx.y*4 + wv;
    if(ct>=CT) return;
    int rt0 = blockIdx.x*2;
    const bf16x8* Ap = Af + (size_t)rt0*704 + l;
    const bf16x8* Bp = Wf + (size_t)ct *704 + l;
    f32x4 acc0={0.f,0.f,0.f,0.f}, acc1={0.f,0.f,0.f,0.f};
    #pragma unroll
    for(int kb=0;kb<11;kb++){
        bf16x8 b  = Bp[kb*64];
        bf16x8 a0 = Ap[kb*64];
        bf16x8 a1 = Ap[704 + kb*64];
        acc0 = __builtin_amdgcn_mfma_f32_16x16x32_bf16(a0,b,acc0,0,0,0);
        acc1 = __builtin_amdgcn_mfma_f32_16x16x32_bf16(a1,b,acc1,0,0,0);
    }
    int col = ct*16 + (l&15);
    int r   = rt0*16 + (l>>4)*4;
    float bb = bias ? bias[col] : 0.f;
    #pragma unroll
    for(int rr=0;rr<4;rr++){
        size_t o0 = (size_t)(r+rr)*CW + col;
        size_t o1 = (size_t)(r+16+rr)*CW + col;
        float v0 = acc0[rr] + bb;
        float v1 = acc1[rr] + bb;
        if(addterm){ v0 += b2f(addterm[o0]); v1 += b2f(addterm[o1]); }
        if(relu){ v0 = fmaxf(v0,0.f); v1 = fmaxf(v1,0.f); }
        C[o0]=v0; C[o1]=v1;
    }
}

__global__ __launch_bounds__(256) void k_attn2(const float* __restrict__ qkv, short* __restrict__ aof){
    __shared__ float ss[8*1008];
    __shared__ float sc[256];
    __shared__ float aos[8*336];
    int n=blockIdx.x, tid=threadIdx.x;
    const float* src = qkv + (size_t)n*8064;
    for(int f=tid; f<8064; f+=256) ss[f]=src[f];
    __syncthreads();
    {
        int h=tid>>6, s=(tid>>3)&7, t=tid&7;
        const float* qp=ss + s*1008 + h*84;
        const float* kp=ss + t*1008 + 336 + h*84;
        float d=0.f;
        for(int d0=0;d0<84;d0++) d+=qp[d0]*kp[d0];
        sc[tid]=d*0.10910894511799619f;
    }
    __syncthreads();
    if(tid<32){
        float* row = sc + (tid>>3)*64 + (tid&7)*8;
        float m=row[0];
        #pragma unroll
        for(int t=1;t<8;t++) m=fmaxf(m,row[t]);
        float sum=0.f;
        #pragma unroll
        for(int t=0;t<8;t++){ float e=__expf(row[t]-m); row[t]=e; sum+=e; }
        float r=1.f/sum;
        #pragma unroll
        for(int t=0;t<8;t++) row[t]*=r;
    }
    __syncthreads();
    for(int o=tid;o<336;o+=256){
        int h=o/84;
        float acc[8];
        #pragma unroll
        for(int s=0;s<8;s++) acc[s]=0.f;
        #pragma unroll
        for(int t=0;t<8;t++){
            float v=ss[t*1008+672+o];
            #pragma unroll
            for(int s=0;s<8;s++) acc[s]+=sc[h*64+s*8+t]*v;
        }
        #pragma unroll
        for(int s=0;s<8;s++) aos[s*336+o]=acc[s];
    }
    __syncthreads();
    int rt=n>>1, half=n&1;
    for(int e=tid; e<2816; e+=256){
        int row=e&7, k=e>>3;
        float v = (k<336)? aos[row*336+k] : 0.f;
        int l = (half*8+row) | (((k>>3)&3)<<4);
        int j = k&7;
        aof[(size_t)rt*5632 + (size_t)(k>>5)*512 + l*8 + j] = bf16r(v);
    }
}

extern "C" void kernel_launch(void* const* d_in, const int* in_sizes, int n_in,
                              void* d_out, int out_size, void* d_ws, size_t ws_size,
                              hipStream_t stream) {
    const float* x    = (const float*)d_in[0];
    const int*   hi   = (const int*  )d_in[1];
    const float* hcw  = (const float*)d_in[2];
    const float* hcb  = (const float*)d_in[3];
    const float* cw   = (const float*)d_in[4];
    const float* cb   = (const float*)d_in[5];
    const float* bng  = (const float*)d_in[6];
    const float* bnb  = (const float*)d_in[7];
    const float* pw   = (const float*)d_in[8];
    const float* pb   = (const float*)d_in[9];
    const float* wq   = (const float*)d_in[10];
    const float* bq   = (const float*)d_in[11];
    const float* wk   = (const float*)d_in[12];
    const float* bk   = (const float*)d_in[13];
    const float* wv   = (const float*)d_in[14];
    const float* bv   = (const float*)d_in[15];
    const float* ipw  = (const float*)d_in[16];
    const float* ipb  = (const float*)d_in[17];
    const float* opw  = (const float*)d_in[18];
    const float* opb  = (const float*)d_in[19];
    const float* fcw  = (const float*)d_in[20];
    const float* fcb  = (const float*)d_in[21];
    float* ws  = (float*)d_ws;
    float* out = (float*)d_out;

    unsigned* stgE = (unsigned*)(ws + O_SEQ);
    int* gcurE = (int*)(ws + O_SEQ) + (size_t)NBUK*BCAP;
    int* gcurD = gcurE + NBUK;
    unsigned* stgD = (unsigned*)(ws + O_AO);
    int* SD = (int*)(ws + O_SD);      // startE | cntE | startD | cntD
    short* W1F = (short*)(ws + O_WF);
    short* W2F = W1F + (size_t)63*5632;

    hipMemsetAsync(ws + O_BN, 0, 64*sizeof(float), stream);
    k_initcur<<<3,256,0,stream>>>(gcurE, gcurD);

    k_bn_stats<<<512,256,0,stream>>>(x, ws+O_BN);
    k_bn_final<<<1,64,0,stream>>>(ws+O_BN, bng, bnb);
    k_xt<<<2048,256,0,stream>>>(x, hcw, (ushort_t*)(ws+O_A));
    k_fusew2<<<231,256,0,stream>>>(ipw, ipb, wq, wk, wv, bq, bk, bv,
                                   fcw, opw, opb, fcb, W1F, W2F, ws+O_BE);

    k_bin<<<NBUK,256,0,stream>>>(hi+EINC, hi, gcurE, stgE);       // group by edge
    k_bin<<<NBUK,256,0,stream>>>(hi, hi+EINC, gcurD, stgD);       // group by node
    k_csrsort<<<NBUK,256,0,stream>>>(stgE, gcurE, SD, SD+NODES);
    k_csrsort<<<NBUK,256,0,stream>>>(stgD, gcurD, SD+2*(size_t)NODES, SD+3*(size_t)NODES);

    // hop 1: edge-grouped gather of xt rows -> e
    k_gath<<<86016,256,0,stream>>>((const ushort_t*)(ws+O_A), (const int*)stgE,
                                   SD, SD+NODES, (ushort_t*)(ws+O_B));
    // hop 2: node-grouped gather of e rows -> h (overwrites xt)
    k_gath<<<86016,256,0,stream>>>((const ushort_t*)(ws+O_B), (const int*)stgD,
                                   SD+2*(size_t)NODES, SD+3*(size_t)NODES, (ushort_t*)(ws+O_A));

    // e dead -> O_B becomes seqf/aof/qkv pool
    k_seq<<<2048,256,0,stream>>>((const ushort_t*)(ws+O_A), hcb, cw, cb, (short*)(ws+O_SEQF));
    // h dead -> O_A becomes res (bf16)
    k_res<<<2048,256,0,stream>>>(x, ws+O_BN, pw, pb, ws+O_BE+1008, (ushort_t*)(ws+O_A));
    {   dim3 g1(512,16);
        k_gemm<<<g1,256,0,stream>>>((const bf16x8*)(ws+O_SEQF),(const bf16x8*)W1F,
                                    nullptr, ws+O_BE, ws+O_QKV, 63, 1008, 0); }
    k_attn2<<<2048,256,0,stream>>>(ws+O_QKV, (short*)(ws+O_AOF));
    {   dim3 g2(512,42);
        k_gemm<<<g2,256,0,stream>>>((const bf16x8*)(ws+O_AOF),(const bf16x8*)W2F,
                                    (const ushort_t*)(ws+O_A), nullptr, out, 168, 2688, 1); }
}

// Round 7
// 1017.646 us; speedup vs baseline: 5.1143x; 1.0306x over previous
//
#include <hip/hip_runtime.h>

#define N_    2048
#define CIN   16
#define T_    8
#define VM_   42
#define COUT  64
#define NODES (N_*T_*VM_)        // 688128
#define EINC  (4*NODES)          // 2752512
#define EMB   336
#define PERN  (T_*VM_*COUT)      // 21504
#define XPERN (CIN*T_*VM_)       // 5376
#define NBUK  672
#define BCAP  4608
#define LCAP  16

typedef __attribute__((ext_vector_type(8))) short bf16x8;
typedef __attribute__((ext_vector_type(4))) float f32x4;
typedef unsigned short ushort_t;
typedef unsigned char  uchar_t;

// ---- ws layout (floats) ----
static const size_t O_A   = 0;                        // xt(fp8) -> h(fp8) -> res(bf16)
static const size_t SZ_AB = (size_t)NODES*64;
static const size_t O_B   = SZ_AB;                    // e(fp8) -> seqf/aof/qkv pool
static const size_t O_SEQ = 2*SZ_AB;                  // stagingE + gcurE/gcurD
static const size_t SZ_SEQ= (size_t)N_*8*EMB;
static const size_t O_AO  = O_SEQ+SZ_SEQ;             // stagingD
static const size_t O_SD  = O_AO+SZ_SEQ;              // startE,cntE,startD,cntD
static const size_t O_BN  = O_SD + 4*(size_t)NODES;
static const size_t O_BE  = O_BN + 64;
static const size_t O_WF  = O_BE + 4096;              // W1F+W2F frags
// sub-pool inside O_B (after e dead):
static const size_t O_SEQF = O_B;                 // 1024*5632 sh
static const size_t O_AOF  = O_B + 3600000;       // 1024*5632 sh
static const size_t O_QKV  = O_B + 6600000;       // 16384*1008 bf16

__device__ inline short bf16r(float f){
    unsigned u = __builtin_bit_cast(unsigned, f);
    u += 0x7FFFu + ((u>>16)&1u);
    return (short)(u>>16);
}
__device__ inline float b2f(ushort_t u){
    return __builtin_bit_cast(float, ((unsigned)u)<<16);
}
__device__ inline uchar_t f2fp8(float f){
    return (uchar_t)(__builtin_amdgcn_cvt_pk_fp8_f32(f,f,0,false)&0xFFu);
}

__global__ __launch_bounds__(256) void k_bn_stats(const float* __restrict__ x, float* __restrict__ bn){
    int b=blockIdx.x, ci=b&15, grp=b>>4;
    int w=threadIdx.x>>6, lane=threadIdx.x&63;
    float s=0.f,q=0.f;
    for(int i=0;i<16;i++){
        int n = grp*64 + w*16 + i;
        const float4* r4 = (const float4*)(x + (size_t)n*XPERN + ci*336);
        for(int k=lane;k<84;k+=64){
            float4 v=r4[k];
            s += v.x+v.y+v.z+v.w;
            q += v.x*v.x+v.y*v.y+v.z*v.z+v.w*v.w;
        }
    }
    for(int off=32;off;off>>=1){ s+=__shfl_down(s,off); q+=__shfl_down(q,off); }
    if(lane==0){ atomicAdd(bn+ci,s); atomicAdd(bn+16+ci,q); }
}

__global__ void k_bn_final(float* bn, const float* __restrict__ g, const float* __restrict__ b){
    int c = threadIdx.x;
    if(c<16){
        const float inv = 1.f/(float)NODES;
        float mean = bn[c]*inv;
        float var  = bn[16+c]*inv - mean*mean;
        float rs   = rsqrtf(var+1e-5f);
        float sc   = g[c]*rs;
        bn[32+c] = sc;
        bn[48+c] = b[c]-mean*sc;
    }
}

__global__ __launch_bounds__(256) void k_xt(const float* __restrict__ x, const float* __restrict__ hcw, uchar_t* __restrict__ xt){
    __shared__ float xs[5376];
    int n=blockIdx.x, tid=threadIdx.x;
    const float4* xr4=(const float4*)(x+(size_t)n*XPERN);
    float4* xs4=(float4*)xs;
    for(int f=tid; f<1344; f+=256) xs4[f]=xr4[f];
    int co=tid&63, q=tid>>6;
    float w[16];
    #pragma unroll
    for(int ci=0;ci<16;ci++) w[ci]=hcw[co*16+ci];
    __syncthreads();
    uchar_t* xn = xt + (size_t)n*336*64;
    for(int g=0; g<21; g++){
        int tl0 = q*84 + g*4;
        float4 acc={0.f,0.f,0.f,0.f};
        #pragma unroll
        for(int ci=0;ci<16;ci++){
            float4 xv = *(const float4*)(xs + ci*336 + tl0);
            acc.x+=xv.x*w[ci]; acc.y+=xv.y*w[ci]; acc.z+=xv.z*w[ci]; acc.w+=xv.w*w[ci];
        }
        xn[(size_t)(tl0+0)*64+co]=f2fp8(acc.x);
        xn[(size_t)(tl0+1)*64+co]=f2fp8(acc.y);
        xn[(size_t)(tl0+2)*64+co]=f2fp8(acc.z);
        xn[(size_t)(tl0+3)*64+co]=f2fp8(acc.w);
    }
}

__global__ void k_initcur(int* __restrict__ gcurE, int* __restrict__ gcurD){
    int i=blockIdx.x*256+threadIdx.x;
    if(i<NBUK){ gcurE[i]=i*BCAP; gcurD[i]=i*BCAP; }
}

__global__ __launch_bounds__(256) void k_bin(const int* __restrict__ seg, const int* __restrict__ pay,
                                             int* __restrict__ gcur, unsigned* __restrict__ staging){
    __shared__ unsigned bins[NBUK*LCAP];
    __shared__ int lcnt[NBUK];
    int tid=threadIdx.x;
    for(int i=tid;i<NBUK;i+=256) lcnt[i]=0;
    __syncthreads();
    int base=blockIdx.x*4096;
    for(int k=0;k<16;k++){
        int i=base+k*256+tid;
        int sv=seg[i], pv=pay[i];
        int b=sv>>10;
        unsigned e=((unsigned)(sv&1023)<<20)|(unsigned)pv;
        int p=atomicAdd(&lcnt[b],1);
        if(p<LCAP) bins[b*LCAP+p]=e;
        else{
            int g=atomicAdd(&gcur[b],1);
            if(g<(b+1)*BCAP) staging[g]=e;
        }
    }
    __syncthreads();
    for(int b=tid;b<NBUK;b+=256){
        int c=lcnt[b]; if(c>LCAP)c=LCAP;
        if(c>0){
            int g=atomicAdd(&gcur[b],c);
            int lim=(b+1)*BCAP;
            for(int j=0;j<c;j++) if(g+j<lim) staging[g+j]=bins[b*LCAP+j];
        }
    }
}

__global__ __launch_bounds__(256) void k_csrsort(unsigned* __restrict__ staging, const int* __restrict__ gcur,
                                                 int* __restrict__ startX, int* __restrict__ cntX){
    __shared__ unsigned ents[BCAP];
    __shared__ unsigned outp[BCAP];
    __shared__ int segc[1024];
    __shared__ int wsum[4];
    int b=blockIdx.x, tid=threadIdx.x, lane=tid&63, wv=tid>>6;
    int cnt_b = gcur[b] - b*BCAP;
    if(cnt_b>BCAP) cnt_b=BCAP;
    unsigned* sb = staging + (size_t)b*BCAP;
    for(int i=tid;i<cnt_b;i+=256) ents[i]=sb[i];
    for(int i=tid;i<1024;i+=256) segc[i]=0;
    __syncthreads();
    for(int i=tid;i<cnt_b;i+=256) atomicAdd(&segc[ents[i]>>20],1);
    __syncthreads();
    int c0=segc[tid*4],c1=segc[tid*4+1],c2=segc[tid*4+2],c3=segc[tid*4+3];
    int tsum=c0+c1+c2+c3;
    int incl=tsum;
    #pragma unroll
    for(int off=1;off<64;off<<=1){ int v=__shfl_up(incl,off); if(lane>=off) incl+=v; }
    if(lane==63) wsum[wv]=incl;
    __syncthreads();
    int w0=wsum[0],w1=wsum[1],w2=wsum[2];
    int wexcl = (wv>0?w0:0)+(wv>1?w1:0)+(wv>2?w2:0);
    int run = incl - tsum + wexcl;
    int gs = b*1024 + tid*4;
    startX[gs+0]=b*BCAP+run; cntX[gs+0]=c0; segc[tid*4+0]=run; run+=c0;
    startX[gs+1]=b*BCAP+run; cntX[gs+1]=c1; segc[tid*4+1]=run; run+=c1;
    startX[gs+2]=b*BCAP+run; cntX[gs+2]=c2; segc[tid*4+2]=run; run+=c2;
    startX[gs+3]=b*BCAP+run; cntX[gs+3]=c3; segc[tid*4+3]=run; run+=c3;
    __syncthreads();
    for(int i=tid;i<cnt_b;i+=256){
        unsigned e=ents[i]; int s=e>>20;
        int p=atomicAdd(&segc[s],1);
        outp[p]=e&0xFFFFFu;
    }
    __syncthreads();
    for(int i=tid;i<cnt_b;i+=256) sb[i]=outp[i];
}

// 2 segments per wave; 32-lane groups; fp8 rows (64B), f32 accumulate
__global__ __launch_bounds__(256) void k_gath(const uchar_t* __restrict__ src, const int* __restrict__ csr,
                                              const int* __restrict__ startX, const int* __restrict__ cntX,
                                              uchar_t* __restrict__ dst){
    int s = blockIdx.x*8 + (threadIdx.x>>5);
    int l = threadIdx.x & 31;
    int c = cntX[s];
    int start = startX[s];
    float ax=0.f, ay=0.f;
    int nv = (c<32)? c : 32;
    int myidx = (l<nv)? csr[start+l] : 0;
    for(int j=0;j<nv;j++){
        int idx = __shfl(myidx, j, 32);
        unsigned v = *(const ushort_t*)(src + (size_t)idx*64 + l*2);
        ax += __builtin_amdgcn_cvt_f32_fp8(v,0);
        ay += __builtin_amdgcn_cvt_f32_fp8(v,1);
    }
    for(int j=32;j<c;j++){
        int idx = csr[start+j];
        unsigned v = *(const ushort_t*)(src + (size_t)idx*64 + l*2);
        ax += __builtin_amdgcn_cvt_f32_fp8(v,0);
        ay += __builtin_amdgcn_cvt_f32_fp8(v,1);
    }
    float scale = (c>0)? 1.f/(float)c : 0.f;
    unsigned p = __builtin_amdgcn_cvt_pk_fp8_f32(ax*scale, ay*scale, 0, false);
    *(ushort_t*)(dst + (size_t)s*64 + l*2) = (ushort_t)(p&0xFFFFu);
}

// temporal conv + direct bf16 fragment emission
__global__ __launch_bounds__(256) void k_seq(const uchar_t* __restrict__ h,
                                             const float* __restrict__ hcb, const float* __restrict__ cw,
                                             const float* __restrict__ cb, short* __restrict__ seqf){
    __shared__ float hb[64], cws[64], cbs[8];
    int n = blockIdx.x, tid=threadIdx.x;
    if(tid<64){ hb[tid]=hcb[tid]; cws[tid]=cw[tid]; }
    if(tid<8) cbs[tid]=cb[tid];
    __syncthreads();
    const uchar_t* hn = h + (size_t)n*PERN;
    int rbase = (n&1)*8;
    short* d0 = seqf + (size_t)(n>>1)*5632;
    for(int e=tid; e<336; e+=256){
        int k = e/42, u = e%42;
        float hv[8];
        #pragma unroll
        for(int t=0;t<8;t++){
            int idx = 2688*k + t*42 + u;
            hv[t] = __builtin_amdgcn_cvt_f32_fp8((unsigned)hn[idx],0) + hb[idx&63];
        }
        int lpart = ((e>>3)&3)<<4;
        size_t obase = (size_t)(e>>5)*512 + (e&7);
        #pragma unroll
        for(int o=0;o<8;o++){
            float acc=cbs[o];
            #pragma unroll
            for(int t=0;t<8;t++) acc += cws[o*8+t]*hv[t];
            d0[obase + (size_t)((rbase+o)|lpart)*8] = bf16r(acc);
        }
    }
    if(tid<128){
        int o=tid>>4, kk=336+(tid&15);
        int l=(rbase+o)|(((kk>>3)&3)<<4);
        d0[(size_t)(kk>>5)*512 + (size_t)l*8 + (kk&7)] = 0;
    }
}

__global__ __launch_bounds__(256) void k_fusew2(const float* __restrict__ ipw, const float* __restrict__ ipb,
        const float* __restrict__ wq, const float* __restrict__ wk, const float* __restrict__ wv,
        const float* __restrict__ bq, const float* __restrict__ bk, const float* __restrict__ bv,
        const float* __restrict__ fcw, const float* __restrict__ opw,
        const float* __restrict__ opb, const float* __restrict__ fcb,
        short* __restrict__ W1F, short* __restrict__ W2F, float* __restrict__ BE){
    __shared__ float As[5376], Ws[5376], bms[336];
    int rt=blockIdx.x, r0=rt*16, tid=threadIdx.x;
    int m=(r0<1008)?(r0/336):3;
    const float* Asrc = (m<3)? (ipw+(size_t)r0*336) : (fcw+(size_t)(r0-1008)*336);
    const float* Bmat = (m==0)?wq:((m==1)?wk:((m==2)?wv:opw));
    const float* bvec = (m==0)?bq:((m==1)?bk:((m==2)?bv:opb));
    for(int f=tid;f<5376;f+=256) As[f]=Asrc[f];
    for(int f=tid;f<336;f+=256) bms[f]=bvec[f];
    __syncthreads();
    if(tid<168){
        int i0=tid, i1=tid+168;
        float a0[16], a1[16];
        #pragma unroll
        for(int r=0;r<16;r++){a0[r]=0.f;a1[r]=0.f;}
        for(int k=0;k<336;k++){
            float b0=Bmat[(size_t)k*336+i0];
            float b1=Bmat[(size_t)k*336+i1];
            #pragma unroll
            for(int r=0;r<16;r++){ float av=As[r*336+k]; a0[r]+=av*b0; a1[r]+=av*b1; }
        }
        #pragma unroll
        for(int r=0;r<16;r++){ Ws[r*336+i0]=a0[r]; Ws[r*336+i1]=a1[r]; }
    }
    if(tid>=192 && tid<208){
        int rr=tid-192;
        float acc=(m<3)? ipb[r0+rr] : fcb[r0+rr-1008];
        for(int k=0;k<336;k++) acc+=As[rr*336+k]*bms[k];
        BE[r0+rr]=acc;
    }
    __syncthreads();
    short* dst=(m<3)? (W1F+(size_t)rt*5632) : (W2F+(size_t)(rt-63)*5632);
    for(int f=tid; f<5632; f+=256){
        int kb=f>>9, rem=f&511, l=rem>>3, j=rem&7;
        int row=l&15, k=kb*32+((l>>4)<<3)+j;
        dst[f] = (k<336)? bf16r(Ws[row*336+k]) : (short)0;
    }
}

__global__ __launch_bounds__(256) void k_res(const float* __restrict__ x, const float* __restrict__ bn,
                                             const float* __restrict__ pw, const float* __restrict__ pb,
                                             const float* __restrict__ bfc, ushort_t* __restrict__ res){
    __shared__ float xp[5376], pws[1024], pbs[64], scs[16], shs[16];
    int n=blockIdx.x, tid=threadIdx.x;
    if(tid<16){ scs[tid]=bn[32+tid]; shs[tid]=bn[48+tid]; }
    if(tid<64) pbs[tid]=pb[tid];
    for(int f=tid;f<1024;f+=256) pws[f]=pw[f];
    __syncthreads();
    const float* xn = x + (size_t)n*XPERN;
    for(int f=tid;f<5376;f+=256){ int ci=f/336; xp[f]=xn[f]*scs[ci]+shs[ci]; }
    __syncthreads();
    ushort_t* rn = res + (size_t)n*PERN;
    for(int j=tid;j<2688;j+=256){
        int co=j&63, w=j>>6;
        float base = bfc[j]+pbs[co];
        float a[8];
        #pragma unroll
        for(int s=0;s<8;s++) a[s]=base;
        #pragma unroll
        for(int ci=0;ci<16;ci++){
            float c=pws[co*16+ci];
            const float* xr = xp + ci*336 + w;
            #pragma unroll
            for(int s=0;s<8;s++) a[s]+=c*xr[s*42];
        }
        #pragma unroll
        for(int s=0;s<8;s++) rn[s*2688+j]=(ushort_t)bf16r(a[s]);
    }
}

// QKV GEMM, bf16 out via LDS-staged coalesced epilogue
__global__ __launch_bounds__(256) void k_gemm_qkv(const bf16x8* __restrict__ Af, const bf16x8* __restrict__ Wf,
                                                  const float* __restrict__ bias, ushort_t* __restrict__ C){
    __shared__ float stage[32][68];
    int wv = threadIdx.x>>6, l = threadIdx.x&63;
    int ct = blockIdx.y*4 + wv;
    int rt0 = blockIdx.x*2;
    if(ct<63){
        const bf16x8* Ap = Af + (size_t)rt0*704 + l;
        const bf16x8* Bp = Wf + (size_t)ct *704 + l;
        f32x4 acc0={0.f,0.f,0.f,0.f}, acc1={0.f,0.f,0.f,0.f};
        #pragma unroll
        for(int kb=0;kb<11;kb++){
            bf16x8 b  = Bp[kb*64];
            bf16x8 a0 = Ap[kb*64];
            bf16x8 a1 = Ap[704 + kb*64];
            acc0 = __builtin_amdgcn_mfma_f32_16x16x32_bf16(a0,b,acc0,0,0,0);
            acc1 = __builtin_amdgcn_mfma_f32_16x16x32_bf16(a1,b,acc1,0,0,0);
        }
        int cc=wv*16+(l&15), rr0=(l>>4)*4;
        float bb = bias[ct*16+(l&15)];
        #pragma unroll
        for(int r=0;r<4;r++){
            stage[rr0+r][cc]    = acc0[r]+bb;
            stage[rr0+16+r][cc] = acc1[r]+bb;
        }
    }
    __syncthreads();
    int lr=threadIdx.x>>3, q=threadIdx.x&7;
    int col0 = blockIdx.y*64 + q*8;
    if(col0<1008){
        short u8[8];
        #pragma unroll
        for(int j=0;j<8;j++) u8[j]=bf16r(stage[lr][q*8+j]);
        *(bf16x8*)(C + (size_t)(rt0*16+lr)*1008 + col0) = *(bf16x8*)u8;
    }
}

// FC GEMM + bf16 res add + relu, f32 out via LDS-staged coalesced epilogue
__global__ __launch_bounds__(256) void k_gemm_out(const bf16x8* __restrict__ Af, const bf16x8* __restrict__ Wf,
                                                  const ushort_t* __restrict__ res, float* __restrict__ C){
    __shared__ float stage[32][68];
    int wv = threadIdx.x>>6, l = threadIdx.x&63;
    int ct = blockIdx.y*4 + wv;
    int rt0 = blockIdx.x*2;
    {
        const bf16x8* Ap = Af + (size_t)rt0*704 + l;
        const bf16x8* Bp = Wf + (size_t)ct *704 + l;
        f32x4 acc0={0.f,0.f,0.f,0.f}, acc1={0.f,0.f,0.f,0.f};
        #pragma unroll
        for(int kb=0;kb<11;kb++){
            bf16x8 b  = Bp[kb*64];
            bf16x8 a0 = Ap[kb*64];
            bf16x8 a1 = Ap[704 + kb*64];
            acc0 = __builtin_amdgcn_mfma_f32_16x16x32_bf16(a0,b,acc0,0,0,0);
            acc1 = __builtin_amdgcn_mfma_f32_16x16x32_bf16(a1,b,acc1,0,0,0);
        }
        int cc=wv*16+(l&15), rr0=(l>>4)*4;
        #pragma unroll
        for(int r=0;r<4;r++){
            stage[rr0+r][cc]    = acc0[r];
            stage[rr0+16+r][cc] = acc1[r];
        }
    }
    __syncthreads();
    int lr=threadIdx.x>>3, q=threadIdx.x&7;
    int row = rt0*16 + lr;
    int col0 = blockIdx.y*64 + q*8;
    bf16x8 rv = *(const bf16x8*)(res + (size_t)row*2688 + col0);
    float v[8];
    #pragma unroll
    for(int j=0;j<8;j++){
        float t = stage[lr][q*8+j] + b2f((ushort_t)rv[j]);
        v[j] = fmaxf(t,0.f);
    }
    float* dst = C + (size_t)row*2688 + col0;
    float4 f0={v[0],v[1],v[2],v[3]}, f1={v[4],v[5],v[6],v[7]};
    *(float4*)dst = f0;
    *(float4*)(dst+4) = f1;
}

__global__ __launch_bounds__(256) void k_attn2(const ushort_t* __restrict__ qkv, short* __restrict__ aof){
    __shared__ float ss[8*1008];
    __shared__ float sc[256];
    __shared__ float aos[8*336];
    int n=blockIdx.x, tid=threadIdx.x;
    const bf16x8* src8 = (const bf16x8*)(qkv + (size_t)n*8064);
    for(int i=tid; i<1008; i+=256){
        bf16x8 v = src8[i];
        #pragma unroll
        for(int j=0;j<8;j++) ss[i*8+j]=b2f((ushort_t)v[j]);
    }
    __syncthreads();
    {
        int h=tid>>6, s=(tid>>3)&7, t=tid&7;
        const float* qp=ss + s*1008 + h*84;
        const float* kp=ss + t*1008 + 336 + h*84;
        float d=0.f;
        for(int d0=0;d0<84;d0++) d+=qp[d0]*kp[d0];
        sc[tid]=d*0.10910894511799619f;
    }
    __syncthreads();
    if(tid<32){
        float* row = sc + (tid>>3)*64 + (tid&7)*8;
        float m=row[0];
        #pragma unroll
        for(int t=1;t<8;t++) m=fmaxf(m,row[t]);
        float sum=0.f;
        #pragma unroll
        for(int t=0;t<8;t++){ float e=__expf(row[t]-m); row[t]=e; sum+=e; }
        float r=1.f/sum;
        #pragma unroll
        for(int t=0;t<8;t++) row[t]*=r;
    }
    __syncthreads();
    for(int o=tid;o<336;o+=256){
        int h=o/84;
        float acc[8];
        #pragma unroll
        for(int s=0;s<8;s++) acc[s]=0.f;
        #pragma unroll
        for(int t=0;t<8;t++){
            float v=ss[t*1008+672+o];
            #pragma unroll
            for(int s=0;s<8;s++) acc[s]+=sc[h*64+s*8+t]*v;
        }
        #pragma unroll
        for(int s=0;s<8;s++) aos[s*336+o]=acc[s];
    }
    __syncthreads();
    int rt=n>>1, half=n&1;
    for(int e=tid; e<2816; e+=256){
        int row=e&7, k=e>>3;
        float v = (k<336)? aos[row*336+k] : 0.f;
        int l = (half*8+row) | (((k>>3)&3)<<4);
        int j = k&7;
        aof[(size_t)rt*5632 + (size_t)(k>>5)*512 + l*8 + j] = bf16r(v);
    }
}

extern "C" void kernel_launch(void* const* d_in, const int* in_sizes, int n_in,
                              void* d_out, int out_size, void* d_ws, size_t ws_size,
                              hipStream_t stream) {
    const float* x    = (const float*)d_in[0];
    const int*   hi   = (const int*  )d_in[1];
    const float* hcw  = (const float*)d_in[2];
    const float* hcb  = (const float*)d_in[3];
    const float* cw   = (const float*)d_in[4];
    const float* cb   = (const float*)d_in[5];
    const float* bng  = (const float*)d_in[6];
    const float* bnb  = (const float*)d_in[7];
    const float* pw   = (const float*)d_in[8];
    const float* pb   = (const float*)d_in[9];
    const float* wq   = (const float*)d_in[10];
    const float* bq   = (const float*)d_in[11];
    const float* wk   = (const float*)d_in[12];
    const float* bk   = (const float*)d_in[13];
    const float* wv   = (const float*)d_in[14];
    const float* bv   = (const float*)d_in[15];
    const float* ipw  = (const float*)d_in[16];
    const float* ipb  = (const float*)d_in[17];
    const float* opw  = (const float*)d_in[18];
    const float* opb  = (const float*)d_in[19];
    const float* fcw  = (const float*)d_in[20];
    const float* fcb  = (const float*)d_in[21];
    float* ws  = (float*)d_ws;
    float* out = (float*)d_out;

    unsigned* stgE = (unsigned*)(ws + O_SEQ);
    int* gcurE = (int*)(ws + O_SEQ) + (size_t)NBUK*BCAP;
    int* gcurD = gcurE + NBUK;
    unsigned* stgD = (unsigned*)(ws + O_AO);
    int* SD = (int*)(ws + O_SD);
    short* W1F = (short*)(ws + O_WF);
    short* W2F = W1F + (size_t)63*5632;
    ushort_t* qkvp = (ushort_t*)(ws + O_QKV);

    hipMemsetAsync(ws + O_BN, 0, 64*sizeof(float), stream);
    k_initcur<<<3,256,0,stream>>>(gcurE, gcurD);

    k_bn_stats<<<512,256,0,stream>>>(x, ws+O_BN);
    k_bn_final<<<1,64,0,stream>>>(ws+O_BN, bng, bnb);
    k_xt<<<2048,256,0,stream>>>(x, hcw, (uchar_t*)(ws+O_A));
    k_fusew2<<<231,256,0,stream>>>(ipw, ipb, wq, wk, wv, bq, bk, bv,
                                   fcw, opw, opb, fcb, W1F, W2F, ws+O_BE);

    k_bin<<<NBUK,256,0,stream>>>(hi+EINC, hi, gcurE, stgE);
    k_bin<<<NBUK,256,0,stream>>>(hi, hi+EINC, gcurD, stgD);
    k_csrsort<<<NBUK,256,0,stream>>>(stgE, gcurE, SD, SD+NODES);
    k_csrsort<<<NBUK,256,0,stream>>>(stgD, gcurD, SD+2*(size_t)NODES, SD+3*(size_t)NODES);

    // hop 1: edge-grouped gather of xt rows -> e (fp8)
    k_gath<<<86016,256,0,stream>>>((const uchar_t*)(ws+O_A), (const int*)stgE,
                                   SD, SD+NODES, (uchar_t*)(ws+O_B));
    // hop 2: node-grouped gather of e rows -> h (fp8, overwrites xt)
    k_gath<<<86016,256,0,stream>>>((const uchar_t*)(ws+O_B), (const int*)stgD,
                                   SD+2*(size_t)NODES, SD+3*(size_t)NODES, (uchar_t*)(ws+O_A));

    // e dead -> O_B becomes seqf/aof/qkv pool
    k_seq<<<2048,256,0,stream>>>((const uchar_t*)(ws+O_A), hcb, cw, cb, (short*)(ws+O_SEQF));
    // h dead -> O_A becomes res (bf16)
    k_res<<<2048,256,0,stream>>>(x, ws+O_BN, pw, pb, ws+O_BE+1008, (ushort_t*)(ws+O_A));
    {   dim3 g1(512,16);
        k_gemm_qkv<<<g1,256,0,stream>>>((const bf16x8*)(ws+O_SEQF),(const bf16x8*)W1F,
                                        ws+O_BE, qkvp); }
    k_attn2<<<2048,256,0,stream>>>(qkvp, (short*)(ws+O_AOF));
    {   dim3 g2(512,42);
        k_gemm_out<<<g2,256,0,stream>>>((const bf16x8*)(ws+O_AOF),(const bf16x8*)W2F,
                                        (const ushort_t*)(ws+O_A), out); }
}

// Round 8
// 938.039 us; speedup vs baseline: 5.5484x; 1.0849x over previous
//
#include <hip/hip_runtime.h>

#define N_    2048
#define CIN   16
#define T_    8
#define VM_   42
#define COUT  64
#define NODES (N_*T_*VM_)        // 688128
#define EINC  (4*NODES)          // 2752512
#define EMB   336
#define PERN  (T_*VM_*COUT)      // 21504
#define XPERN (CIN*T_*VM_)       // 5376
#define NBUK  672
#define BCAP  4608
#define LCAP  16

typedef __attribute__((ext_vector_type(8))) short bf16x8;
typedef __attribute__((ext_vector_type(4))) float f32x4;
typedef unsigned short ushort_t;
typedef unsigned char  uchar_t;

// ---- ws layout (floats) ----
static const size_t O_A   = 0;                        // xt(fp8) -> h(fp8) -> res(bf16)
static const size_t SZ_AB = (size_t)NODES*64;
static const size_t O_B   = SZ_AB;                    // e(fp8) -> seqf/aof/qkv pool
static const size_t O_SEQ = 2*SZ_AB;                  // stagingE + gcurE/gcurD
static const size_t SZ_SEQ= (size_t)N_*8*EMB;
static const size_t O_AO  = O_SEQ+SZ_SEQ;             // stagingD
static const size_t O_SD  = O_AO+SZ_SEQ;              // startE,cntE,startD,cntD
static const size_t O_BN  = O_SD + 4*(size_t)NODES;
static const size_t O_BE  = O_BN + 64;
static const size_t O_WF  = O_BE + 4096;              // W1F+W2F frags
// sub-pool inside O_B (after e dead):
static const size_t O_SEQF = O_B;                 // 1024*5632 sh
static const size_t O_AOF  = O_B + 3600000;       // 1024*5632 sh
static const size_t O_QKV  = O_B + 6600000;       // 16384*1008 bf16

__device__ inline short bf16r(float f){
    unsigned u = __builtin_bit_cast(unsigned, f);
    u += 0x7FFFu + ((u>>16)&1u);
    return (short)(u>>16);
}
__device__ inline float b2f(ushort_t u){
    return __builtin_bit_cast(float, ((unsigned)u)<<16);
}
__device__ inline uchar_t f2fp8(float f){
    return (uchar_t)(__builtin_amdgcn_cvt_pk_fp8_f32(f,f,0,false)&0xFFu);
}

__global__ __launch_bounds__(256) void k_bn_stats(const float* __restrict__ x, float* __restrict__ bn){
    int b=blockIdx.x, ci=b&15, grp=b>>4;
    int w=threadIdx.x>>6, lane=threadIdx.x&63;
    float s=0.f,q=0.f;
    for(int i=0;i<16;i++){
        int n = grp*64 + w*16 + i;
        const float4* r4 = (const float4*)(x + (size_t)n*XPERN + ci*336);
        for(int k=lane;k<84;k+=64){
            float4 v=r4[k];
            s += v.x+v.y+v.z+v.w;
            q += v.x*v.x+v.y*v.y+v.z*v.z+v.w*v.w;
        }
    }
    for(int off=32;off;off>>=1){ s+=__shfl_down(s,off); q+=__shfl_down(q,off); }
    if(lane==0){ atomicAdd(bn+ci,s); atomicAdd(bn+16+ci,q); }
}

__global__ void k_bn_final(float* bn, const float* __restrict__ g, const float* __restrict__ b){
    int c = threadIdx.x;
    if(c<16){
        const float inv = 1.f/(float)NODES;
        float mean = bn[c]*inv;
        float var  = bn[16+c]*inv - mean*mean;
        float rs   = rsqrtf(var+1e-5f);
        float sc   = g[c]*rs;
        bn[32+c] = sc;
        bn[48+c] = b[c]-mean*sc;
    }
}

__global__ __launch_bounds__(256) void k_xt(const float* __restrict__ x, const float* __restrict__ hcw, uchar_t* __restrict__ xt){
    __shared__ float xs[5376];
    int n=blockIdx.x, tid=threadIdx.x;
    const float4* xr4=(const float4*)(x+(size_t)n*XPERN);
    float4* xs4=(float4*)xs;
    for(int f=tid; f<1344; f+=256) xs4[f]=xr4[f];
    int co=tid&63, q=tid>>6;
    float w[16];
    #pragma unroll
    for(int ci=0;ci<16;ci++) w[ci]=hcw[co*16+ci];
    __syncthreads();
    uchar_t* xn = xt + (size_t)n*336*64;
    for(int g=0; g<21; g++){
        int tl0 = q*84 + g*4;
        float4 acc={0.f,0.f,0.f,0.f};
        #pragma unroll
        for(int ci=0;ci<16;ci++){
            float4 xv = *(const float4*)(xs + ci*336 + tl0);
            acc.x+=xv.x*w[ci]; acc.y+=xv.y*w[ci]; acc.z+=xv.z*w[ci]; acc.w+=xv.w*w[ci];
        }
        xn[(size_t)(tl0+0)*64+co]=f2fp8(acc.x);
        xn[(size_t)(tl0+1)*64+co]=f2fp8(acc.y);
        xn[(size_t)(tl0+2)*64+co]=f2fp8(acc.z);
        xn[(size_t)(tl0+3)*64+co]=f2fp8(acc.w);
    }
}

__global__ void k_initcur(int* __restrict__ gcurE, int* __restrict__ gcurD){
    int i=blockIdx.x*256+threadIdx.x;
    if(i<NBUK){ gcurE[i]=i*BCAP; gcurD[i]=i*BCAP; }
}

__global__ __launch_bounds__(256) void k_bin(const int* __restrict__ seg, const int* __restrict__ pay,
                                             int* __restrict__ gcur, unsigned* __restrict__ staging){
    __shared__ unsigned bins[NBUK*LCAP];
    __shared__ int lcnt[NBUK];
    int tid=threadIdx.x;
    for(int i=tid;i<NBUK;i+=256) lcnt[i]=0;
    __syncthreads();
    int base=blockIdx.x*4096;
    for(int k=0;k<16;k++){
        int i=base+k*256+tid;
        int sv=seg[i], pv=pay[i];
        int b=sv>>10;
        unsigned e=((unsigned)(sv&1023)<<20)|(unsigned)pv;
        int p=atomicAdd(&lcnt[b],1);
        if(p<LCAP) bins[b*LCAP+p]=e;
        else{
            int g=atomicAdd(&gcur[b],1);
            if(g<(b+1)*BCAP) staging[g]=e;
        }
    }
    __syncthreads();
    for(int b=tid;b<NBUK;b+=256){
        int c=lcnt[b]; if(c>LCAP)c=LCAP;
        if(c>0){
            int g=atomicAdd(&gcur[b],c);
            int lim=(b+1)*BCAP;
            for(int j=0;j<c;j++) if(g+j<lim) staging[g+j]=bins[b*LCAP+j];
        }
    }
}

__global__ __launch_bounds__(256) void k_csrsort(unsigned* __restrict__ staging, const int* __restrict__ gcur,
                                                 int* __restrict__ startX, int* __restrict__ cntX){
    __shared__ unsigned ents[BCAP];
    __shared__ unsigned outp[BCAP];
    __shared__ int segc[1024];
    __shared__ int wsum[4];
    int b=blockIdx.x, tid=threadIdx.x, lane=tid&63, wv=tid>>6;
    int cnt_b = gcur[b] - b*BCAP;
    if(cnt_b>BCAP) cnt_b=BCAP;
    unsigned* sb = staging + (size_t)b*BCAP;
    for(int i=tid;i<cnt_b;i+=256) ents[i]=sb[i];
    for(int i=tid;i<1024;i+=256) segc[i]=0;
    __syncthreads();
    for(int i=tid;i<cnt_b;i+=256) atomicAdd(&segc[ents[i]>>20],1);
    __syncthreads();
    int c0=segc[tid*4],c1=segc[tid*4+1],c2=segc[tid*4+2],c3=segc[tid*4+3];
    int tsum=c0+c1+c2+c3;
    int incl=tsum;
    #pragma unroll
    for(int off=1;off<64;off<<=1){ int v=__shfl_up(incl,off); if(lane>=off) incl+=v; }
    if(lane==63) wsum[wv]=incl;
    __syncthreads();
    int w0=wsum[0],w1=wsum[1],w2=wsum[2];
    int wexcl = (wv>0?w0:0)+(wv>1?w1:0)+(wv>2?w2:0);
    int run = incl - tsum + wexcl;
    int gs = b*1024 + tid*4;
    startX[gs+0]=b*BCAP+run; cntX[gs+0]=c0; segc[tid*4+0]=run; run+=c0;
    startX[gs+1]=b*BCAP+run; cntX[gs+1]=c1; segc[tid*4+1]=run; run+=c1;
    startX[gs+2]=b*BCAP+run; cntX[gs+2]=c2; segc[tid*4+2]=run; run+=c2;
    startX[gs+3]=b*BCAP+run; cntX[gs+3]=c3; segc[tid*4+3]=run; run+=c3;
    __syncthreads();
    for(int i=tid;i<cnt_b;i+=256){
        unsigned e=ents[i]; int s=e>>20;
        int p=atomicAdd(&segc[s],1);
        outp[p]=e&0xFFFFFu;
    }
    __syncthreads();
    for(int i=tid;i<cnt_b;i+=256) sb[i]=outp[i];
}

// 2 segments per wave; 32-lane groups; fp8 rows (64B), f32 accumulate
__global__ __launch_bounds__(256) void k_gath(const uchar_t* __restrict__ src, const int* __restrict__ csr,
                                              const int* __restrict__ startX, const int* __restrict__ cntX,
                                              uchar_t* __restrict__ dst){
    int s = blockIdx.x*8 + (threadIdx.x>>5);
    int l = threadIdx.x & 31;
    int c = cntX[s];
    int start = startX[s];
    float ax=0.f, ay=0.f;
    int nv = (c<32)? c : 32;
    int myidx = (l<nv)? csr[start+l] : 0;
    for(int j=0;j<nv;j++){
        int idx = __shfl(myidx, j, 32);
        unsigned v = *(const ushort_t*)(src + (size_t)idx*64 + l*2);
        ax += __builtin_amdgcn_cvt_f32_fp8(v,0);
        ay += __builtin_amdgcn_cvt_f32_fp8(v,1);
    }
    for(int j=32;j<c;j++){
        int idx = csr[start+j];
        unsigned v = *(const ushort_t*)(src + (size_t)idx*64 + l*2);
        ax += __builtin_amdgcn_cvt_f32_fp8(v,0);
        ay += __builtin_amdgcn_cvt_f32_fp8(v,1);
    }
    float scale = (c>0)? 1.f/(float)c : 0.f;
    unsigned p = __builtin_amdgcn_cvt_pk_fp8_f32(ax*scale, ay*scale, 0, false);
    *(ushort_t*)(dst + (size_t)s*64 + l*2) = (ushort_t)(p&0xFFFFu);
}

// temporal conv + direct bf16 fragment emission
__global__ __launch_bounds__(256) void k_seq(const uchar_t* __restrict__ h,
                                             const float* __restrict__ hcb, const float* __restrict__ cw,
                                             const float* __restrict__ cb, short* __restrict__ seqf){
    __shared__ float hb[64], cws[64], cbs[8];
    int n = blockIdx.x, tid=threadIdx.x;
    if(tid<64){ hb[tid]=hcb[tid]; cws[tid]=cw[tid]; }
    if(tid<8) cbs[tid]=cb[tid];
    __syncthreads();
    const uchar_t* hn = h + (size_t)n*PERN;
    int rbase = (n&1)*8;
    short* d0 = seqf + (size_t)(n>>1)*5632;
    for(int e=tid; e<336; e+=256){
        int k = e/42, u = e%42;
        float hv[8];
        #pragma unroll
        for(int t=0;t<8;t++){
            int idx = 2688*k + t*42 + u;
            hv[t] = __builtin_amdgcn_cvt_f32_fp8((unsigned)hn[idx],0) + hb[idx&63];
        }
        int lpart = ((e>>3)&3)<<4;
        size_t obase = (size_t)(e>>5)*512 + (e&7);
        #pragma unroll
        for(int o=0;o<8;o++){
            float acc=cbs[o];
            #pragma unroll
            for(int t=0;t<8;t++) acc += cws[o*8+t]*hv[t];
            d0[obase + (size_t)((rbase+o)|lpart)*8] = bf16r(acc);
        }
    }
    if(tid<128){
        int o=tid>>4, kk=336+(tid&15);
        int l=(rbase+o)|(((kk>>3)&3)<<4);
        d0[(size_t)(kk>>5)*512 + (size_t)l*8 + (kk&7)] = 0;
    }
}

__global__ __launch_bounds__(256) void k_fusew2(const float* __restrict__ ipw, const float* __restrict__ ipb,
        const float* __restrict__ wq, const float* __restrict__ wk, const float* __restrict__ wv,
        const float* __restrict__ bq, const float* __restrict__ bk, const float* __restrict__ bv,
        const float* __restrict__ fcw, const float* __restrict__ opw,
        const float* __restrict__ opb, const float* __restrict__ fcb,
        short* __restrict__ W1F, short* __restrict__ W2F, float* __restrict__ BE){
    __shared__ float As[5376], Ws[5376], bms[336];
    int rt=blockIdx.x, r0=rt*16, tid=threadIdx.x;
    int m=(r0<1008)?(r0/336):3;
    const float* Asrc = (m<3)? (ipw+(size_t)r0*336) : (fcw+(size_t)(r0-1008)*336);
    const float* Bmat = (m==0)?wq:((m==1)?wk:((m==2)?wv:opw));
    const float* bvec = (m==0)?bq:((m==1)?bk:((m==2)?bv:opb));
    for(int f=tid;f<5376;f+=256) As[f]=Asrc[f];
    for(int f=tid;f<336;f+=256) bms[f]=bvec[f];
    __syncthreads();
    if(tid<168){
        int i0=tid, i1=tid+168;
        float a0[16], a1[16];
        #pragma unroll
        for(int r=0;r<16;r++){a0[r]=0.f;a1[r]=0.f;}
        for(int k=0;k<336;k++){
            float b0=Bmat[(size_t)k*336+i0];
            float b1=Bmat[(size_t)k*336+i1];
            #pragma unroll
            for(int r=0;r<16;r++){ float av=As[r*336+k]; a0[r]+=av*b0; a1[r]+=av*b1; }
        }
        #pragma unroll
        for(int r=0;r<16;r++){ Ws[r*336+i0]=a0[r]; Ws[r*336+i1]=a1[r]; }
    }
    if(tid>=192 && tid<208){
        int rr=tid-192;
        float acc=(m<3)? ipb[r0+rr] : fcb[r0+rr-1008];
        for(int k=0;k<336;k++) acc+=As[rr*336+k]*bms[k];
        BE[r0+rr]=acc;
    }
    __syncthreads();
    short* dst=(m<3)? (W1F+(size_t)rt*5632) : (W2F+(size_t)(rt-63)*5632);
    for(int f=tid; f<5632; f+=256){
        int kb=f>>9, rem=f&511, l=rem>>3, j=rem&7;
        int row=l&15, k=kb*32+((l>>4)<<3)+j;
        dst[f] = (k<336)? bf16r(Ws[row*336+k]) : (short)0;
    }
}

__global__ __launch_bounds__(256) void k_res(const float* __restrict__ x, const float* __restrict__ bn,
                                             const float* __restrict__ pw, const float* __restrict__ pb,
                                             const float* __restrict__ bfc, ushort_t* __restrict__ res){
    __shared__ float xp[5376], pws[1024], pbs[64], scs[16], shs[16];
    int n=blockIdx.x, tid=threadIdx.x;
    if(tid<16){ scs[tid]=bn[32+tid]; shs[tid]=bn[48+tid]; }
    if(tid<64) pbs[tid]=pb[tid];
    for(int f=tid;f<1024;f+=256) pws[f]=pw[f];
    __syncthreads();
    const float* xn = x + (size_t)n*XPERN;
    for(int f=tid;f<5376;f+=256){ int ci=f/336; xp[f]=xn[f]*scs[ci]+shs[ci]; }
    __syncthreads();
    ushort_t* rn = res + (size_t)n*PERN;
    for(int j=tid;j<2688;j+=256){
        int co=j&63, w=j>>6;
        float base = bfc[j]+pbs[co];
        float a[8];
        #pragma unroll
        for(int s=0;s<8;s++) a[s]=base;
        #pragma unroll
        for(int ci=0;ci<16;ci++){
            float c=pws[co*16+ci];
            const float* xr = xp + ci*336 + w;
            #pragma unroll
            for(int s=0;s<8;s++) a[s]+=c*xr[s*42];
        }
        #pragma unroll
        for(int s=0;s<8;s++) rn[s*2688+j]=(ushort_t)bf16r(a[s]);
    }
}

// Persistent-column QKV GEMM: 8 waves, wave -> 1 col-tile (W frags in regs),
// block streams 16 row-tiles of A through double-buffered LDS.
__global__ __launch_bounds__(512) void k_gemm_qkv(const bf16x8* __restrict__ Af, const bf16x8* __restrict__ Wf,
                                                  const float* __restrict__ bias, ushort_t* __restrict__ C){
    __shared__ short as[2][5632];
    int tid=threadIdx.x, wid=tid>>6, l=tid&63;
    int ct = blockIdx.y*8 + wid;
    bool act = (ct<63);
    bf16x8 Breg[11];
    if(act){
        const bf16x8* Bp = Wf + (size_t)ct*704 + l;
        #pragma unroll
        for(int kb=0;kb<11;kb++) Breg[kb]=Bp[kb*64];
    }
    float bb = act ? bias[ct*16+(l&15)] : 0.f;
    int rt0 = blockIdx.x*16;
    // prologue: stage rt0
    {
        const bf16x8* src = Af + (size_t)rt0*704;
        bf16x8 p0 = src[tid];
        *(bf16x8*)&as[0][tid*8] = p0;
        if(tid<192){ bf16x8 p1 = src[512+tid]; *(bf16x8*)&as[0][(512+tid)*8] = p1; }
    }
    __syncthreads();
    for(int i=0;i<16;i++){
        bf16x8 q0, q1;
        bool pf = (i+1<16);
        if(pf){
            const bf16x8* src = Af + (size_t)(rt0+i+1)*704;
            q0 = src[tid];
            if(tid<192) q1 = src[512+tid];
        }
        f32x4 acc={0.f,0.f,0.f,0.f};
        if(act){
            const short* ab = as[i&1];
            #pragma unroll
            for(int kb=0;kb<11;kb++){
                bf16x8 a = *(const bf16x8*)&ab[(kb*64+l)*8];
                acc = __builtin_amdgcn_mfma_f32_16x16x32_bf16(a,Breg[kb],acc,0,0,0);
            }
            int row0 = (rt0+i)*16 + (l>>4)*4;
            int col  = ct*16 + (l&15);
            #pragma unroll
            for(int rr=0;rr<4;rr++)
                C[(size_t)(row0+rr)*1008 + col] = (ushort_t)bf16r(acc[rr]+bb);
        }
        if(pf){
            *(bf16x8*)&as[(i+1)&1][tid*8] = q0;
            if(tid<192) *(bf16x8*)&as[(i+1)&1][(512+tid)*8] = q1;
        }
        __syncthreads();
    }
}

// Persistent-column FC GEMM + bf16 res add + relu -> f32 out
__global__ __launch_bounds__(512) void k_gemm_out(const bf16x8* __restrict__ Af, const bf16x8* __restrict__ Wf,
                                                  const ushort_t* __restrict__ res, float* __restrict__ C){
    __shared__ short as[2][5632];
    int tid=threadIdx.x, wid=tid>>6, l=tid&63;
    int ct = blockIdx.y*8 + wid;
    bf16x8 Breg[11];
    {
        const bf16x8* Bp = Wf + (size_t)ct*704 + l;
        #pragma unroll
        for(int kb=0;kb<11;kb++) Breg[kb]=Bp[kb*64];
    }
    int rt0 = blockIdx.x*16;
    {
        const bf16x8* src = Af + (size_t)rt0*704;
        bf16x8 p0 = src[tid];
        *(bf16x8*)&as[0][tid*8] = p0;
        if(tid<192){ bf16x8 p1 = src[512+tid]; *(bf16x8*)&as[0][(512+tid)*8] = p1; }
    }
    __syncthreads();
    for(int i=0;i<16;i++){
        bf16x8 q0, q1;
        bool pf = (i+1<16);
        if(pf){
            const bf16x8* src = Af + (size_t)(rt0+i+1)*704;
            q0 = src[tid];
            if(tid<192) q1 = src[512+tid];
        }
        f32x4 acc={0.f,0.f,0.f,0.f};
        {
            const short* ab = as[i&1];
            #pragma unroll
            for(int kb=0;kb<11;kb++){
                bf16x8 a = *(const bf16x8*)&ab[(kb*64+l)*8];
                acc = __builtin_amdgcn_mfma_f32_16x16x32_bf16(a,Breg[kb],acc,0,0,0);
            }
            int row0 = (rt0+i)*16 + (l>>4)*4;
            int col  = ct*16 + (l&15);
            #pragma unroll
            for(int rr=0;rr<4;rr++){
                size_t o = (size_t)(row0+rr)*2688 + col;
                float t = acc[rr] + b2f(res[o]);
                C[o] = fmaxf(t,0.f);
            }
        }
        if(pf){
            *(bf16x8*)&as[(i+1)&1][tid*8] = q0;
            if(tid<192) *(bf16x8*)&as[(i+1)&1][(512+tid)*8] = q1;
        }
        __syncthreads();
    }
}

__global__ __launch_bounds__(256) void k_attn2(const ushort_t* __restrict__ qkv, short* __restrict__ aof){
    __shared__ float ss[8*1008];
    __shared__ float sc[256];
    __shared__ float aos[8*336];
    int n=blockIdx.x, tid=threadIdx.x;
    const bf16x8* src8 = (const bf16x8*)(qkv + (size_t)n*8064);
    for(int i=tid; i<1008; i+=256){
        bf16x8 v = src8[i];
        #pragma unroll
        for(int j=0;j<8;j++) ss[i*8+j]=b2f((ushort_t)v[j]);
    }
    __syncthreads();
    {
        int h=tid>>6, s=(tid>>3)&7, t=tid&7;
        const float* qp=ss + s*1008 + h*84;
        const float* kp=ss + t*1008 + 336 + h*84;
        float d=0.f;
        for(int d0=0;d0<84;d0++) d+=qp[d0]*kp[d0];
        sc[tid]=d*0.10910894511799619f;
    }
    __syncthreads();
    if(tid<32){
        float* row = sc + (tid>>3)*64 + (tid&7)*8;
        float m=row[0];
        #pragma unroll
        for(int t=1;t<8;t++) m=fmaxf(m,row[t]);
        float sum=0.f;
        #pragma unroll
        for(int t=0;t<8;t++){ float e=__expf(row[t]-m); row[t]=e; sum+=e; }
        float r=1.f/sum;
        #pragma unroll
        for(int t=0;t<8;t++) row[t]*=r;
    }
    __syncthreads();
    for(int o=tid;o<336;o+=256){
        int h=o/84;
        float acc[8];
        #pragma unroll
        for(int s=0;s<8;s++) acc[s]=0.f;
        #pragma unroll
        for(int t=0;t<8;t++){
            float v=ss[t*1008+672+o];
            #pragma unroll
            for(int s=0;s<8;s++) acc[s]+=sc[h*64+s*8+t]*v;
        }
        #pragma unroll
        for(int s=0;s<8;s++) aos[s*336+o]=acc[s];
    }
    __syncthreads();
    int rt=n>>1, half=n&1;
    for(int e=tid; e<2816; e+=256){
        int row=e&7, k=e>>3;
        float v = (k<336)? aos[row*336+k] : 0.f;
        int l = (half*8+row) | (((k>>3)&3)<<4);
        int j = k&7;
        aof[(size_t)rt*5632 + (size_t)(k>>5)*512 + l*8 + j] = bf16r(v);
    }
}

extern "C" void kernel_launch(void* const* d_in, const int* in_sizes, int n_in,
                              void* d_out, int out_size, void* d_ws, size_t ws_size,
                              hipStream_t stream) {
    const float* x    = (const float*)d_in[0];
    const int*   hi   = (const int*  )d_in[1];
    const float* hcw  = (const float*)d_in[2];
    const float* hcb  = (const float*)d_in[3];
    const float* cw   = (const float*)d_in[4];
    const float* cb   = (const float*)d_in[5];
    const float* bng  = (const float*)d_in[6];
    const float* bnb  = (const float*)d_in[7];
    const float* pw   = (const float*)d_in[8];
    const float* pb   = (const float*)d_in[9];
    const float* wq   = (const float*)d_in[10];
    const float* bq   = (const float*)d_in[11];
    const float* wk   = (const float*)d_in[12];
    const float* bk   = (const float*)d_in[13];
    const float* wv   = (const float*)d_in[14];
    const float* bv   = (const float*)d_in[15];
    const float* ipw  = (const float*)d_in[16];
    const float* ipb  = (const float*)d_in[17];
    const float* opw  = (const float*)d_in[18];
    const float* opb  = (const float*)d_in[19];
    const float* fcw  = (const float*)d_in[20];
    const float* fcb  = (const float*)d_in[21];
    float* ws  = (float*)d_ws;
    float* out = (float*)d_out;

    unsigned* stgE = (unsigned*)(ws + O_SEQ);
    int* gcurE = (int*)(ws + O_SEQ) + (size_t)NBUK*BCAP;
    int* gcurD = gcurE + NBUK;
    unsigned* stgD = (unsigned*)(ws + O_AO);
    int* SD = (int*)(ws + O_SD);
    short* W1F = (short*)(ws + O_WF);
    short* W2F = W1F + (size_t)63*5632;
    ushort_t* qkvp = (ushort_t*)(ws + O_QKV);

    hipMemsetAsync(ws + O_BN, 0, 64*sizeof(float), stream);
    k_initcur<<<3,256,0,stream>>>(gcurE, gcurD);

    k_bn_stats<<<512,256,0,stream>>>(x, ws+O_BN);
    k_bn_final<<<1,64,0,stream>>>(ws+O_BN, bng, bnb);
    k_xt<<<2048,256,0,stream>>>(x, hcw, (uchar_t*)(ws+O_A));
    k_fusew2<<<231,256,0,stream>>>(ipw, ipb, wq, wk, wv, bq, bk, bv,
                                   fcw, opw, opb, fcb, W1F, W2F, ws+O_BE);

    k_bin<<<NBUK,256,0,stream>>>(hi+EINC, hi, gcurE, stgE);
    k_bin<<<NBUK,256,0,stream>>>(hi, hi+EINC, gcurD, stgD);
    k_csrsort<<<NBUK,256,0,stream>>>(stgE, gcurE, SD, SD+NODES);
    k_csrsort<<<NBUK,256,0,stream>>>(stgD, gcurD, SD+2*(size_t)NODES, SD+3*(size_t)NODES);

    // hop 1: edge-grouped gather of xt rows -> e (fp8)
    k_gath<<<86016,256,0,stream>>>((const uchar_t*)(ws+O_A), (const int*)stgE,
                                   SD, SD+NODES, (uchar_t*)(ws+O_B));
    // hop 2: node-grouped gather of e rows -> h (fp8, overwrites xt)
    k_gath<<<86016,256,0,stream>>>((const uchar_t*)(ws+O_B), (const int*)stgD,
                                   SD+2*(size_t)NODES, SD+3*(size_t)NODES, (uchar_t*)(ws+O_A));

    // e dead -> O_B becomes seqf/aof/qkv pool
    k_seq<<<2048,256,0,stream>>>((const uchar_t*)(ws+O_A), hcb, cw, cb, (short*)(ws+O_SEQF));
    // h dead -> O_A becomes res (bf16)
    k_res<<<2048,256,0,stream>>>(x, ws+O_BN, pw, pb, ws+O_BE+1008, (ushort_t*)(ws+O_A));
    {   dim3 g1(64,8);
        k_gemm_qkv<<<g1,512,0,stream>>>((const bf16x8*)(ws+O_SEQF),(const bf16x8*)W1F,
                                        ws+O_BE, qkvp); }
    k_attn2<<<2048,256,0,stream>>>(qkvp, (short*)(ws+O_AOF));
    {   dim3 g2(64,21);
        k_gemm_out<<<g2,512,0,stream>>>((const bf16x8*)(ws+O_AOF),(const bf16x8*)W2F,
                                        (const ushort_t*)(ws+O_A), out); }
}